// Round 7
// baseline (920.761 us; speedup 1.0000x reference)
//
#include <hip/hip_runtime.h>
#include <hip/hip_bf16.h>
#include <math.h>
#include <stdint.h>

#define EMBED 768
#define NTOK  1024   // 32*32
#define BATCH 4
#define NHEAD 12
#define HD    64
#define MLPD  3072
#define M_ROWS 4096  // BATCH*NTOK

typedef __attribute__((ext_vector_type(8))) short short8;   // 8 x bf16 (4 VGPRs)
typedef __attribute__((ext_vector_type(4))) float floatx4;

__device__ __forceinline__ float b2f(__hip_bfloat16 v) { return __bfloat162float(v); }

// async global->LDS, 16B per lane (GEMM staging; layout lane-contiguous).
__device__ __forceinline__ void gld_lds16(const void* g, void* l) {
    __builtin_amdgcn_global_load_lds(
        (const __attribute__((address_space(1))) uint32_t*)g,
        (__attribute__((address_space(3))) uint32_t*)l, 16, 0, 0);
}

// XOR swizzle for attention tiles: chunk c (8 bf16) of row r at r*64 + ((c^(r&7))*8).
__device__ __forceinline__ int swz(int row, int c) { return row*64 + (((c) ^ (row & 7)) << 3); }

// Bijective XCD-chunked remap (m204 form).
__device__ __forceinline__ void xcd_remap(int gx, int gy, int& bx, int& by) {
    int id  = blockIdx.x + gx*blockIdx.y;
    int nwg = gx*gy;
    int q = nwg >> 3, r = nwg & 7;
    int xcd = id & 7, idx = id >> 3;
    int nid = (xcd < r ? xcd*(q+1) : r*(q+1) + (xcd-r)*q) + idx;
    bx = nid % gx;
    by = nid / gx;
}

// ---------------- im2col: x (4,3,512,512) fp32 -> A_im (4096,768) bf16 --------------
__global__ __launch_bounds__(256)
void im2col(const float* __restrict__ x, __hip_bfloat16* __restrict__ A)
{
    int p  = blockIdx.x;
    int b  = p >> 10;
    int n  = p & 1023;
    int gh = n >> 5, gw = n & 31;
    int tid = threadIdx.x;
    for (int i = tid; i < 768; i += 256) {
        int ci = i >> 8, r = i & 255, kh = r >> 4, kw = r & 15;
        A[(size_t)p*768 + i] = __float2bfloat16(
            x[(((size_t)b*3 + ci)*512 + (gh*16 + kh))*512 + gw*16 + kw]);
    }
}

// ---------------- elementwise fp32 -> bf16 cast -------------------------------------
__global__ __launch_bounds__(256)
void cvt_bf16(const float* __restrict__ in, __hip_bfloat16* __restrict__ out, int n)
{
    int i = blockIdx.x*256 + threadIdx.x;
    if (i < n) out[i] = __float2bfloat16(in[i]);
}

// ---------------- layernorm: fp32 in -> bf16 out ------------------------------------
__global__ __launch_bounds__(256)
void layernorm_bf16(const float* __restrict__ in,
                    const float* __restrict__ w,
                    const float* __restrict__ b,
                    __hip_bfloat16* __restrict__ out)
{
    int row = blockIdx.x;
    const float* xr = in + (size_t)row*768;
    int tid = threadIdx.x;
    float v0 = xr[tid], v1 = xr[tid+256], v2 = xr[tid+512];
    float s = v0+v1+v2, ss = v0*v0+v1*v1+v2*v2;
    __shared__ float rs[256], rss[256];
    rs[tid] = s; rss[tid] = ss; __syncthreads();
    for (int o = 128; o > 0; o >>= 1) {
        if (tid < o) { rs[tid] += rs[tid+o]; rss[tid] += rss[tid+o]; }
        __syncthreads();
    }
    float mean = rs[0] * (1.f/768.f);
    float var  = rss[0] * (1.f/768.f) - mean*mean;
    float inv  = rsqrtf(var + 1e-5f);
    out[(size_t)row*768 + tid]     = __float2bfloat16((v0-mean)*inv*w[tid]     + b[tid]);
    out[(size_t)row*768 + tid+256] = __float2bfloat16((v1-mean)*inv*w[tid+256] + b[tid+256]);
    out[(size_t)row*768 + tid+512] = __float2bfloat16((v2-mean)*inv*w[tid+512] + b[tid+512]);
}

// ---------------- fused: h += p0+p1+bias ; x_ln = LN(h) (next layer ln1) ------------
__global__ __launch_bounds__(256)
void resum_ln(float* __restrict__ h,
              const float* __restrict__ p0, const float* __restrict__ p1,
              const float* __restrict__ bias,
              const float* __restrict__ w, const float* __restrict__ b,
              __hip_bfloat16* __restrict__ out)
{
    int row = blockIdx.x;
    int tid = threadIdx.x;
    size_t base = (size_t)row*768;
    float v[3];
    float s = 0.f, ss = 0.f;
    #pragma unroll
    for (int e = 0; e < 3; ++e) {
        int i = tid + e*256;
        float val = h[base+i] + p0[base+i] + p1[base+i] + bias[i];
        h[base+i] = val;
        v[e] = val; s += val; ss += val*val;
    }
    __shared__ float rs[256], rss[256];
    rs[tid] = s; rss[tid] = ss; __syncthreads();
    for (int o = 128; o > 0; o >>= 1) {
        if (tid < o) { rs[tid] += rs[tid+o]; rss[tid] += rss[tid+o]; }
        __syncthreads();
    }
    float mean = rs[0] * (1.f/768.f);
    float var  = rss[0] * (1.f/768.f) - mean*mean;
    float inv  = rsqrtf(var + 1e-5f);
    #pragma unroll
    for (int e = 0; e < 3; ++e) {
        int i = tid + e*256;
        out[base+i] = __float2bfloat16((v[e]-mean)*inv*w[i] + b[i]);
    }
}

// ---------------- final: out = h + p0 + p1 + bias (fp32) ----------------------------
__global__ __launch_bounds__(256)
void resum_out(const float* __restrict__ h,
               const float* __restrict__ p0, const float* __restrict__ p1,
               const float* __restrict__ bias,
               float* __restrict__ out)
{
    int i = blockIdx.x*256 + threadIdx.x;
    out[i] = h[i] + p0[i] + p1[i] + bias[i % 768];
}

// ---------------- merged weight prep: 4 transposes in one launch --------------------
__global__ __launch_bounds__(256)
void prep_weights(const float* __restrict__ qkv_w,  const float* __restrict__ proj_w,
                  const float* __restrict__ fc1_w,  const float* __restrict__ fc2_w,
                  __hip_bfloat16* __restrict__ qkv_wt, __hip_bfloat16* __restrict__ proj_wt,
                  __hip_bfloat16* __restrict__ fc1_wt, __hip_bfloat16* __restrict__ fc2_wt)
{
    int id = blockIdx.x;
    const float* src; __hip_bfloat16* dst; int K, N, bx, by;
    if (id < 1728)      {            src = qkv_w;  dst = qkv_wt;  K = 768;  N = 2304; bx = id % 72; by = id / 72; }
    else if (id < 2304) { id -= 1728; src = proj_w; dst = proj_wt; K = 768;  N = 768;  bx = id % 24; by = id / 24; }
    else if (id < 4608) { id -= 2304; src = fc1_w;  dst = fc1_wt;  K = 768;  N = 3072; bx = id % 96; by = id / 96; }
    else                { id -= 4608; src = fc2_w;  dst = fc2_wt;  K = 3072; N = 768;  bx = id % 24; by = id / 24; }

    __shared__ float t[32][33];
    int n0 = bx*32, k0 = by*32;
    int tx = threadIdx.x & 31, ty = threadIdx.x >> 5;   // (32, 8)
    #pragma unroll
    for (int r = 0; r < 4; ++r) {
        int row = ty + r*8;
        t[row][tx] = src[(size_t)(k0+row)*N + n0 + tx];
    }
    __syncthreads();
    #pragma unroll
    for (int r = 0; r < 4; ++r) {
        int row = ty + r*8;
        dst[(size_t)(n0+row)*K + k0 + tx] = __float2bfloat16(t[tx][row]);
    }
}

// ---------------- MFMA GEMM, 64x128 tile, reg-dbuf 3-stage pipeline (conv, proj) ----
// grid (N/128, M/64). 4 waves 2x2: wave = 32 rows x 64 cols (2x4 mfma accs).
// One barrier per K-step; ds_read/stage overlap MFMA; 2-step vmcnt prefetch.
__global__ __launch_bounds__(256)
void gemm64(const __hip_bfloat16* __restrict__ A,
            const __hip_bfloat16* __restrict__ Bt,
            const float* __restrict__ bias,
            const float* __restrict__ res,
            const float* __restrict__ posadd,
            float* __restrict__ Cf,
            int M, int N, int K)
{
    // three 12 KB staging buffers: As 64x32 (4 KB) + Bs 128x32 (8 KB) each
    __shared__ __align__(16) char smem[36864];

    const int tid  = threadIdx.x;
    const int lane = tid & 63;
    const int wid  = tid >> 6;
    const int wr   = wid >> 1;          // 0..1 : 32-row half
    const int wc   = wid & 1;           // 0..1 : 64-col half
    const int lr   = lane & 15;
    const int quad = lane >> 4;

    int bx, by;
    xcd_remap(gridDim.x, gridDim.y, bx, by);
    const int bm = by * 64;
    const int bn = bx * 128;

    const int srow  = tid >> 2;         // 0..63
    // bank-deconflict: physical chunk c holds logical chunk c ^ ((row>>1)&3)
    const int skoff = ((tid & 3) ^ ((tid >> 3) & 3)) * 8;
    const int csw   = (quad ^ ((lr >> 1) & 3)) * 8;

    floatx4 acc[2][4];
    #pragma unroll
    for (int i = 0; i < 2; ++i)
        #pragma unroll
        for (int j = 0; j < 4; ++j)
            acc[i][j] = (floatx4){0.f,0.f,0.f,0.f};

    auto stage = [&](int bq, int k0) {
        char* base = smem + bq*12288 + (wid * 1024);
        gld_lds16(A + (size_t)(bm + srow)*K + k0 + skoff, base);
        #pragma unroll
        for (int c = 0; c < 2; ++c)
            gld_lds16(Bt + (size_t)(bn + c*64 + srow)*K + k0 + skoff,
                      base + 4096 + c*4096);
    };
    auto ldread = [&](short8* a, short8* b, int bq) {
        const __hip_bfloat16* As = (const __hip_bfloat16*)(smem + bq*12288);
        const __hip_bfloat16* Bs = As + 2048;   // +4096 bytes
        #pragma unroll
        for (int i = 0; i < 2; ++i)
            a[i] = *(const short8*)((const void*)(As + (wr*32 + i*16 + lr)*32 + csw));
        #pragma unroll
        for (int j = 0; j < 4; ++j)
            b[j] = *(const short8*)((const void*)(Bs + (wc*64 + j*16 + lr)*32 + csw));
    };
    auto mfma8 = [&](short8* a, short8* b) {
        #pragma unroll
        for (int i = 0; i < 2; ++i)
            #pragma unroll
            for (int j = 0; j < 4; ++j)
                acc[i][j] = __builtin_amdgcn_mfma_f32_16x16x32_bf16(a[i], b[j], acc[i][j], 0, 0, 0);
    };

    const int nt = K >> 5;              // 24 for all uses (even, >=6)
    stage(0, 0); stage(1, 32); stage(2, 64);
    asm volatile("s_waitcnt vmcnt(6)" ::: "memory");   // stage(0) landed
    __builtin_amdgcn_s_barrier();
    __builtin_amdgcn_sched_barrier(0);

    short8 aA[2], bA[4], aB[2], bB[4];
    ldread(aA, bA, 0);

    int rb = 1;   // buffer holding step t+1
    int sb = 0;   // buffer to restage at step t (with data t+3)
    for (int t = 0; t < nt; t += 2) {
        // ---- even step t: compute A, read B(t+1), stage(t+3) ----
        asm volatile("s_waitcnt lgkmcnt(0)" ::: "memory");
        __builtin_amdgcn_sched_barrier(0);
        if (t + 3 <= nt) asm volatile("s_waitcnt vmcnt(3)" ::: "memory");
        else             asm volatile("s_waitcnt vmcnt(0)" ::: "memory");
        __builtin_amdgcn_s_barrier();
        __builtin_amdgcn_sched_barrier(0);
        ldread(aB, bB, rb);
        if (t + 3 < nt) stage(sb, (t+3)*32);
        mfma8(aA, bA);
        rb = (rb == 2) ? 0 : rb + 1;
        sb = (sb == 2) ? 0 : sb + 1;

        // ---- odd step t+1: compute B, read A(t+2), stage(t+4) ----
        asm volatile("s_waitcnt lgkmcnt(0)" ::: "memory");
        __builtin_amdgcn_sched_barrier(0);
        if (t + 4 <= nt) asm volatile("s_waitcnt vmcnt(3)" ::: "memory");
        else             asm volatile("s_waitcnt vmcnt(0)" ::: "memory");
        __builtin_amdgcn_s_barrier();
        __builtin_amdgcn_sched_barrier(0);
        if (t + 2 < nt) ldread(aA, bA, rb);
        if (t + 4 < nt) stage(sb, (t+4)*32);
        mfma8(aB, bB);
        rb = (rb == 2) ? 0 : rb + 1;
        sb = (sb == 2) ? 0 : sb + 1;
    }

    // fp32 out (+res, +posadd): direct 64B-chunk stores
    #pragma unroll
    for (int j = 0; j < 4; ++j) {
        int col = bn + wc*64 + j*16 + lr;
        float bs = bias[col];
        #pragma unroll
        for (int i = 0; i < 2; ++i) {
            #pragma unroll
            for (int r = 0; r < 4; ++r) {
                int row = bm + wr*32 + i*16 + quad*4 + r;
                float val = acc[i][j][r] + bs;
                if (res)    val += res[(size_t)row*N + col];
                if (posadd) val += posadd[(size_t)(row & 1023)*N + col];
                Cf[(size_t)row*N + col] = val;
            }
        }
    }
}

// ---------------- MFMA GEMM, 128x128 tile, reg-dbuf 3-stage pipeline (qkv/fc1/fc2) --
// grid (N/128, M/128, S). 4 waves 2x2: wave = 64 rows x 64 cols (4x4 mfma accs).
// emode 1: bf16 Cb (+gelu); emode 2: qkv permute; emode 3: fp32 split-K partial.
__global__ __launch_bounds__(256)
void gemm128(const __hip_bfloat16* __restrict__ A,
             const __hip_bfloat16* __restrict__ Bt,
             const float* __restrict__ bias,
             float* __restrict__ Cf,
             __hip_bfloat16* __restrict__ Cb,
             __hip_bfloat16* __restrict__ qp,
             __hip_bfloat16* __restrict__ kp,
             __hip_bfloat16* __restrict__ vp,
             int M, int N, int K, int S, int dogelu, int emode)
{
    // three 16 KB staging buffers (As 8 KB + Bs 8 KB each); epilogue scratch
    // (4 x 4864 B) aliases the low buffers after the final barrier.
    __shared__ __align__(16) char smem[49152];

    const int tid  = threadIdx.x;
    const int lane = tid & 63;
    const int wid  = tid >> 6;
    const int wr   = wid >> 1;          // 0..1 : 64-row half
    const int wc   = wid & 1;           // 0..1 : 64-col half
    const int lr   = lane & 15;
    const int quad = lane >> 4;

    int bx, by;
    xcd_remap(gridDim.x, gridDim.y, bx, by);
    const int bm = by * 128;
    const int bn = bx * 128;
    const int z  = blockIdx.z;
    const int Kseg = K / S;
    const int kbeg = z * Kseg;

    const int srow  = tid >> 2;         // 0..63
    const int skoff = ((tid & 3) ^ ((tid >> 3) & 3)) * 8;
    const int csw   = (quad ^ ((lr >> 1) & 3)) * 8;

    floatx4 acc[4][4];
    #pragma unroll
    for (int i = 0; i < 4; ++i)
        #pragma unroll
        for (int j = 0; j < 4; ++j)
            acc[i][j] = (floatx4){0.f,0.f,0.f,0.f};

    auto stage = [&](int bq, int k0) {
        char* base = smem + bq*16384 + (wid * 1024);
        #pragma unroll
        for (int c = 0; c < 2; ++c)
            gld_lds16(A + (size_t)(bm + c*64 + srow)*K + k0 + skoff,
                      base + c*4096);
        #pragma unroll
        for (int c = 0; c < 2; ++c)
            gld_lds16(Bt + (size_t)(bn + c*64 + srow)*K + k0 + skoff,
                      base + 8192 + c*4096);
    };
    auto ldread = [&](short8* a, short8* b, int bq) {
        const __hip_bfloat16* As = (const __hip_bfloat16*)(smem + bq*16384);
        const __hip_bfloat16* Bs = As + 4096;   // +8192 bytes
        #pragma unroll
        for (int i = 0; i < 4; ++i)
            a[i] = *(const short8*)((const void*)(As + (wr*64 + i*16 + lr)*32 + csw));
        #pragma unroll
        for (int j = 0; j < 4; ++j)
            b[j] = *(const short8*)((const void*)(Bs + (wc*64 + j*16 + lr)*32 + csw));
    };
    auto mfma16 = [&](short8* a, short8* b) {
        #pragma unroll
        for (int i = 0; i < 4; ++i)
            #pragma unroll
            for (int j = 0; j < 4; ++j)
                acc[i][j] = __builtin_amdgcn_mfma_f32_16x16x32_bf16(a[i], b[j], acc[i][j], 0, 0, 0);
    };

    const int nt = Kseg >> 5;           // 24 or 48 (even, >=6)
    stage(0, kbeg); stage(1, kbeg + 32); stage(2, kbeg + 64);
    asm volatile("s_waitcnt vmcnt(8)" ::: "memory");   // stage(0) landed
    __builtin_amdgcn_s_barrier();
    __builtin_amdgcn_sched_barrier(0);

    short8 aA[4], bA[4], aB[4], bB[4];
    ldread(aA, bA, 0);

    int rb = 1;   // buffer holding step t+1
    int sb = 0;   // buffer to restage at step t (with data t+3)
    for (int t = 0; t < nt; t += 2) {
        // ---- even step t ----
        asm volatile("s_waitcnt lgkmcnt(0)" ::: "memory");
        __builtin_amdgcn_sched_barrier(0);
        if (t + 3 <= nt) asm volatile("s_waitcnt vmcnt(4)" ::: "memory");
        else             asm volatile("s_waitcnt vmcnt(0)" ::: "memory");
        __builtin_amdgcn_s_barrier();
        __builtin_amdgcn_sched_barrier(0);
        ldread(aB, bB, rb);
        if (t + 3 < nt) stage(sb, kbeg + (t+3)*32);
        mfma16(aA, bA);
        rb = (rb == 2) ? 0 : rb + 1;
        sb = (sb == 2) ? 0 : sb + 1;

        // ---- odd step t+1 ----
        asm volatile("s_waitcnt lgkmcnt(0)" ::: "memory");
        __builtin_amdgcn_sched_barrier(0);
        if (t + 4 <= nt) asm volatile("s_waitcnt vmcnt(4)" ::: "memory");
        else             asm volatile("s_waitcnt vmcnt(0)" ::: "memory");
        __builtin_amdgcn_s_barrier();
        __builtin_amdgcn_sched_barrier(0);
        if (t + 2 < nt) ldread(aA, bA, rb);
        if (t + 4 < nt) stage(sb, kbeg + (t+4)*32);
        mfma16(aB, bB);
        rb = (rb == 2) ? 0 : rb + 1;
        sb = (sb == 2) ? 0 : sb + 1;
    }
    // final barrier of the loop has passed; no wave touches staging LDS again
    // -> per-wave epilogue scratch reuse is safe.

    if (emode == 3) {
        // fp32 partials, no bias
        #pragma unroll
        for (int j = 0; j < 4; ++j) {
            int col = bn + wc*64 + j*16 + lr;
            #pragma unroll
            for (int i = 0; i < 4; ++i) {
                #pragma unroll
                for (int r = 0; r < 4; ++r) {
                    int row = bm + wr*64 + i*16 + quad*4 + r;
                    Cf[(size_t)z*M*N + (size_t)row*N + col] = acc[i][j][r];
                }
            }
        }
        return;
    }

    __hip_bfloat16* epi = (__hip_bfloat16*)(smem + wid*4864);

    if (emode == 1) {
        // bf16 out (+gelu), 2 passes of 32 rows through per-wave LDS scratch
        #pragma unroll
        for (int p = 0; p < 2; ++p) {
            #pragma unroll
            for (int j = 0; j < 4; ++j) {
                float bs = bias[bn + wc*64 + j*16 + lr];
                #pragma unroll
                for (int ii = 0; ii < 2; ++ii) {
                    int i = p*2 + ii;
                    #pragma unroll
                    for (int r = 0; r < 4; ++r) {
                        float val = acc[i][j][r] + bs;
                        if (dogelu) val = 0.5f*val*(1.f + erff(val*0.70710678118f));
                        epi[(ii*16 + quad*4 + r)*72 + j*16 + lr] = __float2bfloat16(val);
                    }
                }
            }
            #pragma unroll
            for (int p2 = 0; p2 < 4; ++p2) {
                int row = p2*8 + (lane >> 3), chunk = lane & 7;
                short8 v = *(const short8*)((const void*)(epi + row*72 + chunk*8));
                *(short8*)((void*)(Cb + (size_t)(bm + wr*64 + p*32 + row)*N
                                      + bn + wc*64 + chunk*8)) = v;
            }
        }
        return;
    }

    // emode 2: qkv permute
    const int head64 = (bn + wc*64) >> 6;     // wave's 64 cols = one head slot
    const int which  = head64 / 12;           // 0=q 1=k 2=v
    const int head   = head64 % 12;
    const int b_     = (bm + wr*64) >> 10;
    const int bh     = b_*NHEAD + head;
    const int n0     = (bm + wr*64) & 1023;

    if (which < 2) {
        __hip_bfloat16* dst = (which == 0 ? qp : kp) + ((size_t)bh*NTOK + n0)*HD;
        #pragma unroll
        for (int p = 0; p < 2; ++p) {
            #pragma unroll
            for (int j = 0; j < 4; ++j) {
                float bs = bias[bn + wc*64 + j*16 + lr];
                #pragma unroll
                for (int ii = 0; ii < 2; ++ii) {
                    int i = p*2 + ii;
                    #pragma unroll
                    for (int r = 0; r < 4; ++r)
                        epi[(ii*16 + quad*4 + r)*72 + j*16 + lr] =
                            __float2bfloat16(acc[i][j][r] + bs);
                }
            }
            #pragma unroll
            for (int p2 = 0; p2 < 4; ++p2) {
                int row = p2*8 + (lane >> 3), chunk = lane & 7;
                short8 v = *(const short8*)((const void*)(epi + row*72 + chunk*8));
                *(short8*)((void*)(dst + (size_t)(p*32 + row)*HD + chunk*8)) = v;
            }
        }
    } else {
        // v transposed: [d=64][tok32] per pass, stride 36
        __hip_bfloat16* dstv = vp + (size_t)bh*HD*NTOK + n0;
        #pragma unroll
        for (int p = 0; p < 2; ++p) {
            #pragma unroll
            for (int j = 0; j < 4; ++j) {
                float bs = bias[bn + wc*64 + j*16 + lr];
                #pragma unroll
                for (int ii = 0; ii < 2; ++ii) {
                    int i = p*2 + ii;
                    #pragma unroll
                    for (int r = 0; r < 4; ++r)
                        epi[(j*16 + lr)*36 + ii*16 + quad*4 + r] =
                            __float2bfloat16(acc[i][j][r] + bs);
                }
            }
            #pragma unroll
            for (int p2 = 0; p2 < 4; ++p2) {
                int d = p2*16 + (lane >> 2), chunk = lane & 3;
                short8 v = *(const short8*)((const void*)(epi + d*36 + chunk*8));
                *(short8*)((void*)(dstv + (size_t)d*NTOK + p*32 + chunk*8)) = v;
            }
        }
    }
}

// ---------------- MFMA flash attention, swizzled LDS, shift-free softmax ------------
__global__ __launch_bounds__(256)
void attention_mfma(const __hip_bfloat16* __restrict__ qp,   // [48][1024][64]
                    const __hip_bfloat16* __restrict__ kp,   // [48][1024][64]
                    const __hip_bfloat16* __restrict__ vp,   // [48][64][1024] (V^T)
                    const float* __restrict__ rph,           // (63,64)
                    const float* __restrict__ rpw,           // (63,64)
                    __hip_bfloat16* __restrict__ out)        // (4,1024,768) bf16
{
    const int blk  = blockIdx.x;
    const int bh   = blk >> 4;
    const int qt   = blk & 15;
    const int b    = bh / NHEAD;
    const int head = bh % NHEAD;
    const int tid  = threadIdx.x;
    const int lane = tid & 63;
    const int w    = tid >> 6;
    const int lr   = lane & 15;
    const int quad = lane >> 4;

    __shared__ __align__(16) __hip_bfloat16 Qs[64*64];
    __shared__ __align__(16) __hip_bfloat16 Ks[64*64];      // prologue alias: rph table
    __shared__ __align__(16) __hip_bfloat16 Vs[64*64];      // prologue alias: rpw table
    __shared__ __align__(16) __hip_bfloat16 Ps[4*16*64];
    __shared__ float relhS[64*32];
    __shared__ float relwS[64*32];

    const __hip_bfloat16* qb = qp + ((size_t)bh*NTOK + qt*64)*HD;
    const __hip_bfloat16* kb = kp + (size_t)bh*NTOK*HD;
    const __hip_bfloat16* vb = vp + (size_t)bh*HD*NTOK;

    const int sr = tid >> 2;
    const int sc = (tid & 3) * 2;

    short8 kreg0, kreg1, vreg0, vreg1;
    {
        const __hip_bfloat16* kk = kb + (size_t)sr*HD + sc*8;
        kreg0 = *(const short8*)((const void*)kk);
        kreg1 = *(const short8*)((const void*)(kk + 8));
        const __hip_bfloat16* vv = vb + (size_t)sr*NTOK + sc*8;
        vreg0 = *(const short8*)((const void*)vv);
        vreg1 = *(const short8*)((const void*)(vv + 8));
    }

    {
        const __hip_bfloat16* qq = qb + (size_t)sr*HD + sc*8;
        short8 q0 = *(const short8*)((const void*)qq);
        short8 q1 = *(const short8*)((const void*)(qq + 8));
        *(short8*)((void*)(Qs + swz(sr, sc)))   = q0;
        *(short8*)((void*)(Qs + swz(sr, sc+1))) = q1;
    }

    for (int i = tid; i < 504; i += 256) {
        int r = i >> 3, c = i & 7;
        const float* ph = rph + (size_t)r*HD + c*8;
        const float* pw = rpw + (size_t)r*HD + c*8;
        union { short8 v; __hip_bfloat16 e[8]; } uh, uw;
        #pragma unroll
        for (int e = 0; e < 8; ++e) { uh.e[e] = __float2bfloat16(ph[e]); uw.e[e] = __float2bfloat16(pw[e]); }
        *(short8*)((void*)(Ks + swz(r, c))) = uh.v;
        *(short8*)((void*)(Vs + swz(r, c))) = uw.v;
    }
    if (tid < 16) {
        short8 z = (short8){0,0,0,0,0,0,0,0};
        int c = tid & 7;
        if (tid < 8) *(short8*)((void*)(Ks + swz(63, c))) = z;
        else         *(short8*)((void*)(Vs + swz(63, c))) = z;
    }
    __syncthreads();

    short8 qa0 = *(const short8*)((const void*)(Qs + swz(w*16 + lr, quad)));
    short8 qa1 = *(const short8*)((const void*)(Qs + swz(w*16 + lr, 4 + quad)));

    const int qrow = w*16 + quad*4;
    const int qh_  = qt*2 + (w >> 1);
    const int qw_  = (w & 1)*16 + quad*4;

    #pragma unroll
    for (int j = 0; j < 4; ++j) {
        int t = j*16 + lr;
        short8 th0 = *(const short8*)((const void*)(Ks + swz(j*16 + lr, quad)));
        short8 th1 = *(const short8*)((const void*)(Ks + swz(j*16 + lr, 4 + quad)));
        floatx4 ha = (floatx4){0.f,0.f,0.f,0.f};
        ha = __builtin_amdgcn_mfma_f32_16x16x32_bf16(qa0, th0, ha, 0, 0, 0);
        ha = __builtin_amdgcn_mfma_f32_16x16x32_bf16(qa1, th1, ha, 0, 0, 0);
        short8 tw0 = *(const short8*)((const void*)(Vs + swz(j*16 + lr, quad)));
        short8 tw1 = *(const short8*)((const void*)(Vs + swz(j*16 + lr, 4 + quad)));
        floatx4 wa = (floatx4){0.f,0.f,0.f,0.f};
        wa = __builtin_amdgcn_mfma_f32_16x16x32_bf16(qa0, tw0, wa, 0, 0, 0);
        wa = __builtin_amdgcn_mfma_f32_16x16x32_bf16(qa1, tw1, wa, 0, 0, 0);
        int kh = qh_ + 31 - t;
        #pragma unroll
        for (int rr = 0; rr < 4; ++rr) {
            if (kh >= 0 && kh < 32) relhS[(qrow + rr)*32 + kh] = ha[rr];
            int kw = qw_ + rr + 31 - t;
            if (kw >= 0 && kw < 32) relwS[(qrow + rr)*32 + kw] = wa[rr];
        }
    }

    float rw[4][2];
    #pragma unroll
    for (int rr = 0; rr < 4; ++rr)
        #pragma unroll
        for (int jp = 0; jp < 2; ++jp)
            rw[rr][jp] = relwS[(qrow + rr)*32 + jp*16 + lr];

    floatx4 o[4];
    #pragma unroll
    for (int ds = 0; ds < 4; ++ds) o[ds] = (floatx4){0.f,0.f,0.f,0.f};
    float lsum[4] = {0.f, 0.f, 0.f, 0.f};

    const float scale = 0.125f;

    for (int kt = 0; kt < 16; ++kt) {
        __syncthreads();
        *(short8*)((void*)(Ks + swz(sr, sc)))   = kreg0;
        *(short8*)((void*)(Ks + swz(sr, sc+1))) = kreg1;
        *(short8*)((void*)(Vs + swz(sr, sc)))   = vreg0;
        *(short8*)((void*)(Vs + swz(sr, sc+1))) = vreg1;
        __syncthreads();

        if (kt < 15) {
            const __hip_bfloat16* kk = kb + (size_t)(kt+1)*64*HD + (size_t)sr*HD + sc*8;
            kreg0 = *(const short8*)((const void*)kk);
            kreg1 = *(const short8*)((const void*)(kk + 8));
            const __hip_bfloat16* vv = vb + (size_t)sr*NTOK + (kt+1)*64 + sc*8;
            vreg0 = *(const short8*)((const void*)vv);
            vreg1 = *(const short8*)((const void*)(vv + 8));
        }

        float2 rh2[4];
        #pragma unroll
        for (int rr = 0; rr < 4; ++rr)
            rh2[rr] = *(const float2*)((const void*)(relhS + (qrow + rr)*32 + kt*2));

        floatx4 sv[4];
        #pragma unroll
        for (int j = 0; j < 4; ++j) {
            short8 kb0 = *(const short8*)((const void*)(Ks + swz(j*16 + lr, quad)));
            short8 kb1 = *(const short8*)((const void*)(Ks + swz(j*16 + lr, 4 + quad)));
            floatx4 z = (floatx4){0.f,0.f,0.f,0.f};
            z = __builtin_amdgcn_mfma_f32_16x16x32_bf16(qa0, kb0, z, 0, 0, 0);
            z = __builtin_amdgcn_mfma_f32_16x16x32_bf16(qa1, kb1, z, 0, 0, 0);
            sv[j] = z;
        }

        #pragma unroll
        for (int j = 0; j < 4; ++j) {
            int colc = j*2 + (lr >> 3);
            #pragma unroll
            for (int rr = 0; rr < 4; ++rr) {
                float s = sv[j][rr]*scale + ((j < 2) ? rh2[rr].x : rh2[rr].y) + rw[rr][j & 1];
                s = fminf(fmaxf(s, -60.f), 60.f);
                float pp = __expf(s);
                lsum[rr] += pp;
                int prow = quad*4 + rr;
                Ps[w*1024 + prow*64 + ((colc ^ (prow & 7)) << 3) + (lr & 7)] = __float2bfloat16(pp);
            }
        }

        short8 pa0 = *(const short8*)((const void*)(Ps + w*1024 + swz(lr, quad)));
        short8 pa1 = *(const short8*)((const void*)(Ps + w*1024 + swz(lr, 4 + quad)));
        #pragma unroll
        for (int ds = 0; ds < 4; ++ds) {
            short8 v0 = *(const short8*)((const void*)(Vs + swz(ds*16 + lr, quad)));
            short8 v1 = *(const short8*)((const void*)(Vs + swz(ds*16 + lr, 4 + quad)));
            o[ds] = __builtin_amdgcn_mfma_f32_16x16x32_bf16(pa0, v0, o[ds], 0, 0, 0);
            o[ds] = __builtin_amdgcn_mfma_f32_16x16x32_bf16(pa1, v1, o[ds], 0, 0, 0);
        }
    }

    #pragma unroll
    for (int off = 1; off < 16; off <<= 1)
        #pragma unroll
        for (int rr = 0; rr < 4; ++rr)
            lsum[rr] += __shfl_xor(lsum[rr], off, 16);

    #pragma unroll
    for (int rr = 0; rr < 4; ++rr) {
        float inv = 1.f / lsum[rr];
        int n = qt*64 + w*16 + quad*4 + rr;
        size_t base = ((size_t)b*NTOK + n)*EMBED + head*HD;
        #pragma unroll
        for (int ds = 0; ds < 4; ++ds)
            out[base + ds*16 + lr] = __float2bfloat16(o[ds][rr] * inv);
    }
}

extern "C" void kernel_launch(void* const* d_in, const int* in_sizes, int n_in,
                              void* d_out, int out_size, void* d_ws, size_t ws_size,
                              hipStream_t stream)
{
    const float* x      = (const float*)d_in[0];
    const float* conv_w = (const float*)d_in[1];
    const float* conv_b = (const float*)d_in[2];
    const float* pos    = (const float*)d_in[3];
    const float* ln1_w  = (const float*)d_in[4];
    const float* ln1_b  = (const float*)d_in[5];
    const float* qkv_w  = (const float*)d_in[6];
    const float* qkv_b  = (const float*)d_in[7];
    const float* proj_w = (const float*)d_in[8];
    const float* proj_b = (const float*)d_in[9];
    const float* rph    = (const float*)d_in[10];
    const float* rpw    = (const float*)d_in[11];
    const float* ln2_w  = (const float*)d_in[12];
    const float* ln2_b  = (const float*)d_in[13];
    const float* fc1_w  = (const float*)d_in[14];
    const float* fc1_b  = (const float*)d_in[15];
    const float* fc2_w  = (const float*)d_in[16];
    const float* fc2_b  = (const float*)d_in[17];

    char* p = (char*)d_ws;
    float*           h       = (float*)p;           p += (size_t)M_ROWS*EMBED*4;
    __hip_bfloat16*  q_perm  = (__hip_bfloat16*)p;
    float*           p0      = (float*)p;           p += (size_t)48*NTOK*HD*2;
    __hip_bfloat16*  k_perm  = (__hip_bfloat16*)p;  p += (size_t)48*NTOK*HD*2;
    __hip_bfloat16*  vt_perm = (__hip_bfloat16*)p;  p += (size_t)48*NTOK*HD*2;
    __hip_bfloat16*  attn_o  = (__hip_bfloat16*)p;  p += (size_t)M_ROWS*EMBED*2;
    __hip_bfloat16*  x_ln    = (__hip_bfloat16*)p;  p += (size_t)M_ROWS*EMBED*2;
    __hip_bfloat16*  mlp     = (__hip_bfloat16*)p;  p += (size_t)M_ROWS*MLPD*2;
    __hip_bfloat16*  qkv_wt  = (__hip_bfloat16*)p;  p += (size_t)2304*768*2;
    __hip_bfloat16*  proj_wt = (__hip_bfloat16*)p;  p += (size_t)768*768*2;
    __hip_bfloat16*  fc1_wt  = (__hip_bfloat16*)p;  p += (size_t)MLPD*768*2;
    __hip_bfloat16*  fc2_wt  = (__hip_bfloat16*)p;  p += (size_t)768*MLPD*2;

    __hip_bfloat16*  A_im    = mlp;      // alias: not simultaneously live
    __hip_bfloat16*  conv_wt = qkv_wt;   // alias: overwritten by layer-0 prep

    // ---- patch embed as GEMM (64x128 tiles) ----
    im2col<<<M_ROWS, 256, 0, stream>>>(x, A_im);
    cvt_bf16<<<(768*768 + 255)/256, 256, 0, stream>>>(conv_w, conv_wt, 768*768);
    gemm64<<<dim3(768/128, M_ROWS/64, 1), 256, 0, stream>>>(
        A_im, conv_wt, conv_b, nullptr, pos, h, M_ROWS, 768, 768);

    layernorm_bf16<<<M_ROWS, 256, 0, stream>>>(h, ln1_w, ln1_b, x_ln);

    for (int L = 0; L < 4; ++L) {
        prep_weights<<<6912, 256, 0, stream>>>(
            qkv_w + (size_t)L*768*2304, proj_w + (size_t)L*768*768,
            fc1_w + (size_t)L*768*MLPD, fc2_w + (size_t)L*MLPD*768,
            qkv_wt, proj_wt, fc1_wt, fc2_wt);

        gemm128<<<dim3(2304/128, M_ROWS/128, 1), 256, 0, stream>>>(
            x_ln, qkv_wt, qkv_b + (size_t)L*3*EMBED,
            nullptr, nullptr, q_perm, k_perm, vt_perm,
            M_ROWS, 2304, 768, 1, 0, 2);

        attention_mfma<<<48*16, 256, 0, stream>>>(
            q_perm, k_perm, vt_perm,
            rph + (size_t)L*63*64, rpw + (size_t)L*63*64, attn_o);

        gemm64<<<dim3(768/128, M_ROWS/64, 1), 256, 0, stream>>>(
            attn_o, proj_wt, proj_b + (size_t)L*EMBED, h, nullptr,
            h, M_ROWS, 768, 768);

        layernorm_bf16<<<M_ROWS, 256, 0, stream>>>(h, ln2_w + L*EMBED, ln2_b + L*EMBED, x_ln);

        gemm128<<<dim3(MLPD/128, M_ROWS/128, 1), 256, 0, stream>>>(
            x_ln, fc1_wt, fc1_b + (size_t)L*MLPD,
            nullptr, mlp, nullptr, nullptr, nullptr,
            M_ROWS, MLPD, 768, 1, 1, 1);

        // fc2 split-K=2 -> fp32 partials p0,p1 (alias dead q/k/vt/attn_o region)
        gemm128<<<dim3(768/128, M_ROWS/128, 2), 256, 0, stream>>>(
            mlp, fc2_wt, nullptr,
            p0, nullptr, nullptr, nullptr, nullptr,
            M_ROWS, 768, MLPD, 2, 0, 3);

        float* p1 = p0 + (size_t)M_ROWS*768;
        if (L < 3) {
            resum_ln<<<M_ROWS, 256, 0, stream>>>(
                h, p0, p1, fc2_b + (size_t)L*EMBED,
                ln1_w + (size_t)(L+1)*EMBED, ln1_b + (size_t)(L+1)*EMBED, x_ln);
        } else {
            resum_out<<<M_ROWS*EMBED/256, 256, 0, stream>>>(
                h, p0, p1, fc2_b + (size_t)L*EMBED, (float*)d_out);
        }
    }
}

// Round 9
// 852.994 us; speedup vs baseline: 1.0794x; 1.0794x over previous
//
#include <hip/hip_runtime.h>
#include <hip/hip_bf16.h>
#include <math.h>
#include <stdint.h>

#define EMBED 768
#define NTOK  1024   // 32*32
#define BATCH 4
#define NHEAD 12
#define HD    64
#define MLPD  3072
#define M_ROWS 4096  // BATCH*NTOK

typedef __attribute__((ext_vector_type(8))) short short8;   // 8 x bf16 (4 VGPRs)
typedef __attribute__((ext_vector_type(4))) float floatx4;

__device__ __forceinline__ float b2f(__hip_bfloat16 v) { return __bfloat162float(v); }

// async global->LDS, 16B per lane (GEMM staging; layout lane-contiguous).
__device__ __forceinline__ void gld_lds16(const void* g, void* l) {
    __builtin_amdgcn_global_load_lds(
        (const __attribute__((address_space(1))) uint32_t*)g,
        (__attribute__((address_space(3))) uint32_t*)l, 16, 0, 0);
}

// XOR swizzle for attention tiles: chunk c (8 bf16) of row r at r*64 + ((c^(r&7))*8).
__device__ __forceinline__ int swz(int row, int c) { return row*64 + (((c) ^ (row & 7)) << 3); }

// Bijective XCD-chunked remap (m204 form).
__device__ __forceinline__ void xcd_remap(int gx, int gy, int& bx, int& by) {
    int id  = blockIdx.x + gx*blockIdx.y;
    int nwg = gx*gy;
    int q = nwg >> 3, r = nwg & 7;
    int xcd = id & 7, idx = id >> 3;
    int nid = (xcd < r ? xcd*(q+1) : r*(q+1) + (xcd-r)*q) + idx;
    bx = nid % gx;
    by = nid / gx;
}

// ---------------- im2col: x (4,3,512,512) fp32 -> A_im (4096,768) bf16 --------------
__global__ __launch_bounds__(256)
void im2col(const float* __restrict__ x, __hip_bfloat16* __restrict__ A)
{
    int p  = blockIdx.x;
    int b  = p >> 10;
    int n  = p & 1023;
    int gh = n >> 5, gw = n & 31;
    int tid = threadIdx.x;
    for (int i = tid; i < 768; i += 256) {
        int ci = i >> 8, r = i & 255, kh = r >> 4, kw = r & 15;
        A[(size_t)p*768 + i] = __float2bfloat16(
            x[(((size_t)b*3 + ci)*512 + (gh*16 + kh))*512 + gw*16 + kw]);
    }
}

// ---------------- elementwise fp32 -> bf16 cast -------------------------------------
__global__ __launch_bounds__(256)
void cvt_bf16(const float* __restrict__ in, __hip_bfloat16* __restrict__ out, int n)
{
    int i = blockIdx.x*256 + threadIdx.x;
    if (i < n) out[i] = __float2bfloat16(in[i]);
}

// ---------------- layernorm: fp32 in -> bf16 out ------------------------------------
__global__ __launch_bounds__(256)
void layernorm_bf16(const float* __restrict__ in,
                    const float* __restrict__ w,
                    const float* __restrict__ b,
                    __hip_bfloat16* __restrict__ out)
{
    int row = blockIdx.x;
    const float* xr = in + (size_t)row*768;
    int tid = threadIdx.x;
    float v0 = xr[tid], v1 = xr[tid+256], v2 = xr[tid+512];
    float s = v0+v1+v2, ss = v0*v0+v1*v1+v2*v2;
    __shared__ float rs[256], rss[256];
    rs[tid] = s; rss[tid] = ss; __syncthreads();
    for (int o = 128; o > 0; o >>= 1) {
        if (tid < o) { rs[tid] += rs[tid+o]; rss[tid] += rss[tid+o]; }
        __syncthreads();
    }
    float mean = rs[0] * (1.f/768.f);
    float var  = rss[0] * (1.f/768.f) - mean*mean;
    float inv  = rsqrtf(var + 1e-5f);
    out[(size_t)row*768 + tid]     = __float2bfloat16((v0-mean)*inv*w[tid]     + b[tid]);
    out[(size_t)row*768 + tid+256] = __float2bfloat16((v1-mean)*inv*w[tid+256] + b[tid+256]);
    out[(size_t)row*768 + tid+512] = __float2bfloat16((v2-mean)*inv*w[tid+512] + b[tid+512]);
}

// ---------------- fused: h += p0+p1+bias ; x_ln = LN(h) (next layer ln1) ------------
__global__ __launch_bounds__(256)
void resum_ln(float* __restrict__ h,
              const float* __restrict__ p0, const float* __restrict__ p1,
              const float* __restrict__ bias,
              const float* __restrict__ w, const float* __restrict__ b,
              __hip_bfloat16* __restrict__ out)
{
    int row = blockIdx.x;
    int tid = threadIdx.x;
    size_t base = (size_t)row*768;
    float v[3];
    float s = 0.f, ss = 0.f;
    #pragma unroll
    for (int e = 0; e < 3; ++e) {
        int i = tid + e*256;
        float val = h[base+i] + p0[base+i] + p1[base+i] + bias[i];
        h[base+i] = val;
        v[e] = val; s += val; ss += val*val;
    }
    __shared__ float rs[256], rss[256];
    rs[tid] = s; rss[tid] = ss; __syncthreads();
    for (int o = 128; o > 0; o >>= 1) {
        if (tid < o) { rs[tid] += rs[tid+o]; rss[tid] += rss[tid+o]; }
        __syncthreads();
    }
    float mean = rs[0] * (1.f/768.f);
    float var  = rss[0] * (1.f/768.f) - mean*mean;
    float inv  = rsqrtf(var + 1e-5f);
    #pragma unroll
    for (int e = 0; e < 3; ++e) {
        int i = tid + e*256;
        out[base+i] = __float2bfloat16((v[e]-mean)*inv*w[i] + b[i]);
    }
}

// ---------------- final: out = h + p0 + p1 + bias (fp32) ----------------------------
__global__ __launch_bounds__(256)
void resum_out(const float* __restrict__ h,
               const float* __restrict__ p0, const float* __restrict__ p1,
               const float* __restrict__ bias,
               float* __restrict__ out)
{
    int i = blockIdx.x*256 + threadIdx.x;
    out[i] = h[i] + p0[i] + p1[i] + bias[i % 768];
}

// ---------------- merged weight prep: 4 transposes in one launch --------------------
__global__ __launch_bounds__(256)
void prep_weights(const float* __restrict__ qkv_w,  const float* __restrict__ proj_w,
                  const float* __restrict__ fc1_w,  const float* __restrict__ fc2_w,
                  __hip_bfloat16* __restrict__ qkv_wt, __hip_bfloat16* __restrict__ proj_wt,
                  __hip_bfloat16* __restrict__ fc1_wt, __hip_bfloat16* __restrict__ fc2_wt)
{
    int id = blockIdx.x;
    const float* src; __hip_bfloat16* dst; int K, N, bx, by;
    if (id < 1728)      {            src = qkv_w;  dst = qkv_wt;  K = 768;  N = 2304; bx = id % 72; by = id / 72; }
    else if (id < 2304) { id -= 1728; src = proj_w; dst = proj_wt; K = 768;  N = 768;  bx = id % 24; by = id / 24; }
    else if (id < 4608) { id -= 2304; src = fc1_w;  dst = fc1_wt;  K = 768;  N = 3072; bx = id % 96; by = id / 96; }
    else                { id -= 4608; src = fc2_w;  dst = fc2_wt;  K = 3072; N = 768;  bx = id % 24; by = id / 24; }

    __shared__ float t[32][33];
    int n0 = bx*32, k0 = by*32;
    int tx = threadIdx.x & 31, ty = threadIdx.x >> 5;   // (32, 8)
    #pragma unroll
    for (int r = 0; r < 4; ++r) {
        int row = ty + r*8;
        t[row][tx] = src[(size_t)(k0+row)*N + n0 + tx];
    }
    __syncthreads();
    #pragma unroll
    for (int r = 0; r < 4; ++r) {
        int row = ty + r*8;
        dst[(size_t)(n0+row)*K + k0 + tx] = __float2bfloat16(t[tx][row]);
    }
}

// ---------------- MFMA GEMM, 64x128 tile, counted-vmcnt pipeline (conv, proj) -------
// grid (N/128, M/64). 4 waves 2x2: wave = 32 rows x 64 cols (2x4 mfma accs).
// fp32 out (+res, +posadd). Depth-2 prefetch, no vmcnt(0) drains in the loop.
// launch_bounds(256,3): keep total regs under the 512/3~170 cliff -> 3 waves/SIMD.
__global__ __launch_bounds__(256, 3)
void gemm64(const __hip_bfloat16* __restrict__ A,
            const __hip_bfloat16* __restrict__ Bt,
            const float* __restrict__ bias,
            const float* __restrict__ res,
            const float* __restrict__ posadd,
            float* __restrict__ Cf,
            int M, int N, int K)
{
    // two 12 KB staging buffers: As 64x32 (4 KB) + Bs 128x32 (8 KB) each
    __shared__ __align__(16) char smem[24576];

    const int tid  = threadIdx.x;
    const int lane = tid & 63;
    const int wid  = tid >> 6;
    const int wr   = wid >> 1;          // 0..1 : 32-row half
    const int wc   = wid & 1;           // 0..1 : 64-col half
    const int lr   = lane & 15;
    const int quad = lane >> 4;

    int bx, by;
    xcd_remap(gridDim.x, gridDim.y, bx, by);
    const int bm = by * 64;
    const int bn = bx * 128;

    const int srow  = tid >> 2;         // 0..63
    // bank-deconflict: physical chunk c holds logical chunk c ^ ((row>>1)&3)
    const int skoff = ((tid & 3) ^ ((tid >> 3) & 3)) * 8;
    const int csw   = (quad ^ ((lr >> 1) & 3)) * 8;

    floatx4 acc[2][4];
    #pragma unroll
    for (int i = 0; i < 2; ++i)
        #pragma unroll
        for (int j = 0; j < 4; ++j)
            acc[i][j] = (floatx4){0.f,0.f,0.f,0.f};

    auto stage = [&](int bq, int k0) {
        char* base = smem + bq*12288 + (wid * 1024);
        gld_lds16(A + (size_t)(bm + srow)*K + k0 + skoff, base);
        #pragma unroll
        for (int c = 0; c < 2; ++c)
            gld_lds16(Bt + (size_t)(bn + c*64 + srow)*K + k0 + skoff,
                      base + 4096 + c*4096);
    };

    const int nt = K >> 5;              // >= 2 for all shapes used
    stage(0, 0);
    stage(1, 32);
    int cur = 0;
    for (int t = 0; t < nt; ++t) {
        // own stage(t) = 3 oldest loads; stage(t+1) (3) may stay in flight
        if (t + 1 < nt) asm volatile("s_waitcnt vmcnt(3)" ::: "memory");
        else            asm volatile("s_waitcnt vmcnt(0)" ::: "memory");
        __builtin_amdgcn_s_barrier();

        const __hip_bfloat16* As = (const __hip_bfloat16*)(smem + cur*12288);
        const __hip_bfloat16* Bs = As + 2048;   // +4096 bytes

        short8 a[2], b[4];
        #pragma unroll
        for (int i = 0; i < 2; ++i)
            a[i] = *(const short8*)((const void*)(As + (wr*32 + i*16 + lr)*32 + csw));
        #pragma unroll
        for (int j = 0; j < 4; ++j)
            b[j] = *(const short8*)((const void*)(Bs + (wc*64 + j*16 + lr)*32 + csw));
        asm volatile("s_waitcnt lgkmcnt(0)" ::: "memory");
        __builtin_amdgcn_sched_barrier(0);
        __builtin_amdgcn_s_barrier();   // all waves done reading buf[cur]

        if (t + 2 < nt) stage(cur, (t+2)*32);

        #pragma unroll
        for (int i = 0; i < 2; ++i)
            #pragma unroll
            for (int j = 0; j < 4; ++j)
                acc[i][j] = __builtin_amdgcn_mfma_f32_16x16x32_bf16(a[i], b[j], acc[i][j], 0, 0, 0);
        cur ^= 1;
    }

    // fp32 out (+res, +posadd): direct 64B-chunk stores
    #pragma unroll
    for (int j = 0; j < 4; ++j) {
        int col = bn + wc*64 + j*16 + lr;
        float bs = bias[col];
        #pragma unroll
        for (int i = 0; i < 2; ++i) {
            #pragma unroll
            for (int r = 0; r < 4; ++r) {
                int row = bm + wr*32 + i*16 + quad*4 + r;
                float val = acc[i][j][r] + bs;
                if (res)    val += res[(size_t)row*N + col];
                if (posadd) val += posadd[(size_t)(row & 1023)*N + col];
                Cf[(size_t)row*N + col] = val;
            }
        }
    }
}

// ---------------- MFMA GEMM, 128x128 tile, counted-vmcnt pipeline (qkv/fc1/fc2) -----
// grid (N/128, M/128, S). 4 waves 2x2: wave = 64 rows x 64 cols (4x4 mfma accs).
// emode 1: bf16 Cb (+gelu), LDS-coalesced, 2-pass epilogue
// emode 2: qkv permute (LDS-coalesced, 2-pass)
// emode 3: fp32 partial -> Cf + z*M*N (split-K)
// launch_bounds(256,3): keep total regs under the 512/3~170 cliff -> 3 waves/SIMD.
__global__ __launch_bounds__(256, 3)
void gemm128(const __hip_bfloat16* __restrict__ A,
             const __hip_bfloat16* __restrict__ Bt,
             const float* __restrict__ bias,
             float* __restrict__ Cf,
             __hip_bfloat16* __restrict__ Cb,
             __hip_bfloat16* __restrict__ qp,
             __hip_bfloat16* __restrict__ kp,
             __hip_bfloat16* __restrict__ vp,
             int M, int N, int K, int S, int dogelu, int emode)
{
    // two 16 KB staging buffers (As 8 KB + Bs 8 KB each); epilogue scratch
    // (4 x 4864 B) aliases buffer 0 after the final read-barrier.
    __shared__ __align__(16) char smem[32768];

    const int tid  = threadIdx.x;
    const int lane = tid & 63;
    const int wid  = tid >> 6;
    const int wr   = wid >> 1;          // 0..1 : 64-row half
    const int wc   = wid & 1;           // 0..1 : 64-col half
    const int lr   = lane & 15;
    const int quad = lane >> 4;

    int bx, by;
    xcd_remap(gridDim.x, gridDim.y, bx, by);
    const int bm = by * 128;
    const int bn = bx * 128;
    const int z  = blockIdx.z;
    const int Kseg = K / S;
    const int kbeg = z * Kseg;

    const int srow  = tid >> 2;         // 0..63
    const int skoff = ((tid & 3) ^ ((tid >> 3) & 3)) * 8;
    const int csw   = (quad ^ ((lr >> 1) & 3)) * 8;

    floatx4 acc[4][4];
    #pragma unroll
    for (int i = 0; i < 4; ++i)
        #pragma unroll
        for (int j = 0; j < 4; ++j)
            acc[i][j] = (floatx4){0.f,0.f,0.f,0.f};

    auto stage = [&](int bq, int k0) {
        char* base = smem + bq*16384 + (wid * 1024);
        #pragma unroll
        for (int c = 0; c < 2; ++c)
            gld_lds16(A + (size_t)(bm + c*64 + srow)*K + k0 + skoff,
                      base + c*4096);
        #pragma unroll
        for (int c = 0; c < 2; ++c)
            gld_lds16(Bt + (size_t)(bn + c*64 + srow)*K + k0 + skoff,
                      base + 8192 + c*4096);
    };

    const int nt = Kseg >> 5;           // 24 or 48
    stage(0, kbeg);
    stage(1, kbeg + 32);
    int cur = 0;
    for (int t = 0; t < nt; ++t) {
        // own stage(t) = 4 oldest loads; stage(t+1) (4) may stay in flight
        if (t + 1 < nt) asm volatile("s_waitcnt vmcnt(4)" ::: "memory");
        else            asm volatile("s_waitcnt vmcnt(0)" ::: "memory");
        __builtin_amdgcn_s_barrier();

        const __hip_bfloat16* As = (const __hip_bfloat16*)(smem + cur*16384);
        const __hip_bfloat16* Bs = As + 4096;   // +8192 bytes

        short8 a[4], b[4];
        #pragma unroll
        for (int i = 0; i < 4; ++i)
            a[i] = *(const short8*)((const void*)(As + (wr*64 + i*16 + lr)*32 + csw));
        #pragma unroll
        for (int j = 0; j < 4; ++j)
            b[j] = *(const short8*)((const void*)(Bs + (wc*64 + j*16 + lr)*32 + csw));
        asm volatile("s_waitcnt lgkmcnt(0)" ::: "memory");
        __builtin_amdgcn_sched_barrier(0);
        __builtin_amdgcn_s_barrier();   // all waves done reading buf[cur]

        if (t + 2 < nt) stage(cur, kbeg + (t+2)*32);

        #pragma unroll
        for (int i = 0; i < 4; ++i)
            #pragma unroll
            for (int j = 0; j < 4; ++j)
                acc[i][j] = __builtin_amdgcn_mfma_f32_16x16x32_bf16(a[i], b[j], acc[i][j], 0, 0, 0);
        cur ^= 1;
    }
    // after the final read-barrier all waves are past their LDS reads -> per-wave reuse

    if (emode == 3) {
        // fp32 partials, no bias
        #pragma unroll
        for (int j = 0; j < 4; ++j) {
            int col = bn + wc*64 + j*16 + lr;
            #pragma unroll
            for (int i = 0; i < 4; ++i) {
                #pragma unroll
                for (int r = 0; r < 4; ++r) {
                    int row = bm + wr*64 + i*16 + quad*4 + r;
                    Cf[(size_t)z*M*N + (size_t)row*N + col] = acc[i][j][r];
                }
            }
        }
        return;
    }

    __hip_bfloat16* epi = (__hip_bfloat16*)(smem + wid*4864);

    if (emode == 1) {
        // bf16 out (+gelu), 2 passes of 32 rows through per-wave LDS scratch
        #pragma unroll
        for (int p = 0; p < 2; ++p) {
            #pragma unroll
            for (int j = 0; j < 4; ++j) {
                float bs = bias[bn + wc*64 + j*16 + lr];
                #pragma unroll
                for (int ii = 0; ii < 2; ++ii) {
                    int i = p*2 + ii;
                    #pragma unroll
                    for (int r = 0; r < 4; ++r) {
                        float val = acc[i][j][r] + bs;
                        if (dogelu) val = 0.5f*val*(1.f + erff(val*0.70710678118f));
                        epi[(ii*16 + quad*4 + r)*72 + j*16 + lr] = __float2bfloat16(val);
                    }
                }
            }
            #pragma unroll
            for (int p2 = 0; p2 < 4; ++p2) {
                int row = p2*8 + (lane >> 3), chunk = lane & 7;
                short8 v = *(const short8*)((const void*)(epi + row*72 + chunk*8));
                *(short8*)((void*)(Cb + (size_t)(bm + wr*64 + p*32 + row)*N
                                      + bn + wc*64 + chunk*8)) = v;
            }
        }
        return;
    }

    // emode 2: qkv permute
    const int head64 = (bn + wc*64) >> 6;     // wave's 64 cols = one head slot
    const int which  = head64 / 12;           // 0=q 1=k 2=v
    const int head   = head64 % 12;
    const int b_     = (bm + wr*64) >> 10;
    const int bh     = b_*NHEAD + head;
    const int n0     = (bm + wr*64) & 1023;

    if (which < 2) {
        __hip_bfloat16* dst = (which == 0 ? qp : kp) + ((size_t)bh*NTOK + n0)*HD;
        #pragma unroll
        for (int p = 0; p < 2; ++p) {
            #pragma unroll
            for (int j = 0; j < 4; ++j) {
                float bs = bias[bn + wc*64 + j*16 + lr];
                #pragma unroll
                for (int ii = 0; ii < 2; ++ii) {
                    int i = p*2 + ii;
                    #pragma unroll
                    for (int r = 0; r < 4; ++r)
                        epi[(ii*16 + quad*4 + r)*72 + j*16 + lr] =
                            __float2bfloat16(acc[i][j][r] + bs);
                }
            }
            #pragma unroll
            for (int p2 = 0; p2 < 4; ++p2) {
                int row = p2*8 + (lane >> 3), chunk = lane & 7;
                short8 v = *(const short8*)((const void*)(epi + row*72 + chunk*8));
                *(short8*)((void*)(dst + (size_t)(p*32 + row)*HD + chunk*8)) = v;
            }
        }
    } else {
        // v transposed: [d=64][tok32] per pass, stride 36
        __hip_bfloat16* dstv = vp + (size_t)bh*HD*NTOK + n0;
        #pragma unroll
        for (int p = 0; p < 2; ++p) {
            #pragma unroll
            for (int j = 0; j < 4; ++j) {
                float bs = bias[bn + wc*64 + j*16 + lr];
                #pragma unroll
                for (int ii = 0; ii < 2; ++ii) {
                    int i = p*2 + ii;
                    #pragma unroll
                    for (int r = 0; r < 4; ++r)
                        epi[(j*16 + lr)*36 + ii*16 + quad*4 + r] =
                            __float2bfloat16(acc[i][j][r] + bs);
                }
            }
            #pragma unroll
            for (int p2 = 0; p2 < 4; ++p2) {
                int d = p2*16 + (lane >> 2), chunk = lane & 3;
                short8 v = *(const short8*)((const void*)(epi + d*36 + chunk*8));
                *(short8*)((void*)(dstv + (size_t)d*NTOK + p*32 + chunk*8)) = v;
            }
        }
    }
}

// ---------------- MFMA flash attention, swizzled LDS, shift-free softmax ------------
__global__ __launch_bounds__(256)
void attention_mfma(const __hip_bfloat16* __restrict__ qp,   // [48][1024][64]
                    const __hip_bfloat16* __restrict__ kp,   // [48][1024][64]
                    const __hip_bfloat16* __restrict__ vp,   // [48][64][1024] (V^T)
                    const float* __restrict__ rph,           // (63,64)
                    const float* __restrict__ rpw,           // (63,64)
                    __hip_bfloat16* __restrict__ out)        // (4,1024,768) bf16
{
    const int blk  = blockIdx.x;
    const int bh   = blk >> 4;
    const int qt   = blk & 15;
    const int b    = bh / NHEAD;
    const int head = bh % NHEAD;
    const int tid  = threadIdx.x;
    const int lane = tid & 63;
    const int w    = tid >> 6;
    const int lr   = lane & 15;
    const int quad = lane >> 4;

    __shared__ __align__(16) __hip_bfloat16 Qs[64*64];
    __shared__ __align__(16) __hip_bfloat16 Ks[64*64];      // prologue alias: rph table
    __shared__ __align__(16) __hip_bfloat16 Vs[64*64];      // prologue alias: rpw table
    __shared__ __align__(16) __hip_bfloat16 Ps[4*16*64];
    __shared__ float relhS[64*32];
    __shared__ float relwS[64*32];

    const __hip_bfloat16* qb = qp + ((size_t)bh*NTOK + qt*64)*HD;
    const __hip_bfloat16* kb = kp + (size_t)bh*NTOK*HD;
    const __hip_bfloat16* vb = vp + (size_t)bh*HD*NTOK;

    const int sr = tid >> 2;
    const int sc = (tid & 3) * 2;

    short8 kreg0, kreg1, vreg0, vreg1;
    {
        const __hip_bfloat16* kk = kb + (size_t)sr*HD + sc*8;
        kreg0 = *(const short8*)((const void*)kk);
        kreg1 = *(const short8*)((const void*)(kk + 8));
        const __hip_bfloat16* vv = vb + (size_t)sr*NTOK + sc*8;
        vreg0 = *(const short8*)((const void*)vv);
        vreg1 = *(const short8*)((const void*)(vv + 8));
    }

    {
        const __hip_bfloat16* qq = qb + (size_t)sr*HD + sc*8;
        short8 q0 = *(const short8*)((const void*)qq);
        short8 q1 = *(const short8*)((const void*)(qq + 8));
        *(short8*)((void*)(Qs + swz(sr, sc)))   = q0;
        *(short8*)((void*)(Qs + swz(sr, sc+1))) = q1;
    }

    for (int i = tid; i < 504; i += 256) {
        int r = i >> 3, c = i & 7;
        const float* ph = rph + (size_t)r*HD + c*8;
        const float* pw = rpw + (size_t)r*HD + c*8;
        union { short8 v; __hip_bfloat16 e[8]; } uh, uw;
        #pragma unroll
        for (int e = 0; e < 8; ++e) { uh.e[e] = __float2bfloat16(ph[e]); uw.e[e] = __float2bfloat16(pw[e]); }
        *(short8*)((void*)(Ks + swz(r, c))) = uh.v;
        *(short8*)((void*)(Vs + swz(r, c))) = uw.v;
    }
    if (tid < 16) {
        short8 z = (short8){0,0,0,0,0,0,0,0};
        int c = tid & 7;
        if (tid < 8) *(short8*)((void*)(Ks + swz(63, c))) = z;
        else         *(short8*)((void*)(Vs + swz(63, c))) = z;
    }
    __syncthreads();

    short8 qa0 = *(const short8*)((const void*)(Qs + swz(w*16 + lr, quad)));
    short8 qa1 = *(const short8*)((const void*)(Qs + swz(w*16 + lr, 4 + quad)));

    const int qrow = w*16 + quad*4;
    const int qh_  = qt*2 + (w >> 1);
    const int qw_  = (w & 1)*16 + quad*4;

    #pragma unroll
    for (int j = 0; j < 4; ++j) {
        int t = j*16 + lr;
        short8 th0 = *(const short8*)((const void*)(Ks + swz(j*16 + lr, quad)));
        short8 th1 = *(const short8*)((const void*)(Ks + swz(j*16 + lr, 4 + quad)));
        floatx4 ha = (floatx4){0.f,0.f,0.f,0.f};
        ha = __builtin_amdgcn_mfma_f32_16x16x32_bf16(qa0, th0, ha, 0, 0, 0);
        ha = __builtin_amdgcn_mfma_f32_16x16x32_bf16(qa1, th1, ha, 0, 0, 0);
        short8 tw0 = *(const short8*)((const void*)(Vs + swz(j*16 + lr, quad)));
        short8 tw1 = *(const short8*)((const void*)(Vs + swz(j*16 + lr, 4 + quad)));
        floatx4 wa = (floatx4){0.f,0.f,0.f,0.f};
        wa = __builtin_amdgcn_mfma_f32_16x16x32_bf16(qa0, tw0, wa, 0, 0, 0);
        wa = __builtin_amdgcn_mfma_f32_16x16x32_bf16(qa1, tw1, wa, 0, 0, 0);
        int kh = qh_ + 31 - t;
        #pragma unroll
        for (int rr = 0; rr < 4; ++rr) {
            if (kh >= 0 && kh < 32) relhS[(qrow + rr)*32 + kh] = ha[rr];
            int kw = qw_ + rr + 31 - t;
            if (kw >= 0 && kw < 32) relwS[(qrow + rr)*32 + kw] = wa[rr];
        }
    }

    float rw[4][2];
    #pragma unroll
    for (int rr = 0; rr < 4; ++rr)
        #pragma unroll
        for (int jp = 0; jp < 2; ++jp)
            rw[rr][jp] = relwS[(qrow + rr)*32 + jp*16 + lr];

    floatx4 o[4];
    #pragma unroll
    for (int ds = 0; ds < 4; ++ds) o[ds] = (floatx4){0.f,0.f,0.f,0.f};
    float lsum[4] = {0.f, 0.f, 0.f, 0.f};

    const float scale = 0.125f;

    for (int kt = 0; kt < 16; ++kt) {
        __syncthreads();
        *(short8*)((void*)(Ks + swz(sr, sc)))   = kreg0;
        *(short8*)((void*)(Ks + swz(sr, sc+1))) = kreg1;
        *(short8*)((void*)(Vs + swz(sr, sc)))   = vreg0;
        *(short8*)((void*)(Vs + swz(sr, sc+1))) = vreg1;
        __syncthreads();

        if (kt < 15) {
            const __hip_bfloat16* kk = kb + (size_t)(kt+1)*64*HD + (size_t)sr*HD + sc*8;
            kreg0 = *(const short8*)((const void*)kk);
            kreg1 = *(const short8*)((const void*)(kk + 8));
            const __hip_bfloat16* vv = vb + (size_t)sr*NTOK + (kt+1)*64 + sc*8;
            vreg0 = *(const short8*)((const void*)vv);
            vreg1 = *(const short8*)((const void*)(vv + 8));
        }

        float2 rh2[4];
        #pragma unroll
        for (int rr = 0; rr < 4; ++rr)
            rh2[rr] = *(const float2*)((const void*)(relhS + (qrow + rr)*32 + kt*2));

        floatx4 sv[4];
        #pragma unroll
        for (int j = 0; j < 4; ++j) {
            short8 kb0 = *(const short8*)((const void*)(Ks + swz(j*16 + lr, quad)));
            short8 kb1 = *(const short8*)((const void*)(Ks + swz(j*16 + lr, 4 + quad)));
            floatx4 z = (floatx4){0.f,0.f,0.f,0.f};
            z = __builtin_amdgcn_mfma_f32_16x16x32_bf16(qa0, kb0, z, 0, 0, 0);
            z = __builtin_amdgcn_mfma_f32_16x16x32_bf16(qa1, kb1, z, 0, 0, 0);
            sv[j] = z;
        }

        #pragma unroll
        for (int j = 0; j < 4; ++j) {
            int colc = j*2 + (lr >> 3);
            #pragma unroll
            for (int rr = 0; rr < 4; ++rr) {
                float s = sv[j][rr]*scale + ((j < 2) ? rh2[rr].x : rh2[rr].y) + rw[rr][j & 1];
                s = fminf(fmaxf(s, -60.f), 60.f);
                float pp = __expf(s);
                lsum[rr] += pp;
                int prow = quad*4 + rr;
                Ps[w*1024 + prow*64 + ((colc ^ (prow & 7)) << 3) + (lr & 7)] = __float2bfloat16(pp);
            }
        }

        short8 pa0 = *(const short8*)((const void*)(Ps + w*1024 + swz(lr, quad)));
        short8 pa1 = *(const short8*)((const void*)(Ps + w*1024 + swz(lr, 4 + quad)));
        #pragma unroll
        for (int ds = 0; ds < 4; ++ds) {
            short8 v0 = *(const short8*)((const void*)(Vs + swz(ds*16 + lr, quad)));
            short8 v1 = *(const short8*)((const void*)(Vs + swz(ds*16 + lr, 4 + quad)));
            o[ds] = __builtin_amdgcn_mfma_f32_16x16x32_bf16(pa0, v0, o[ds], 0, 0, 0);
            o[ds] = __builtin_amdgcn_mfma_f32_16x16x32_bf16(pa1, v1, o[ds], 0, 0, 0);
        }
    }

    #pragma unroll
    for (int off = 1; off < 16; off <<= 1)
        #pragma unroll
        for (int rr = 0; rr < 4; ++rr)
            lsum[rr] += __shfl_xor(lsum[rr], off, 16);

    #pragma unroll
    for (int rr = 0; rr < 4; ++rr) {
        float inv = 1.f / lsum[rr];
        int n = qt*64 + w*16 + quad*4 + rr;
        size_t base = ((size_t)b*NTOK + n)*EMBED + head*HD;
        #pragma unroll
        for (int ds = 0; ds < 4; ++ds)
            out[base + ds*16 + lr] = __float2bfloat16(o[ds][rr] * inv);
    }
}

extern "C" void kernel_launch(void* const* d_in, const int* in_sizes, int n_in,
                              void* d_out, int out_size, void* d_ws, size_t ws_size,
                              hipStream_t stream)
{
    const float* x      = (const float*)d_in[0];
    const float* conv_w = (const float*)d_in[1];
    const float* conv_b = (const float*)d_in[2];
    const float* pos    = (const float*)d_in[3];
    const float* ln1_w  = (const float*)d_in[4];
    const float* ln1_b  = (const float*)d_in[5];
    const float* qkv_w  = (const float*)d_in[6];
    const float* qkv_b  = (const float*)d_in[7];
    const float* proj_w = (const float*)d_in[8];
    const float* proj_b = (const float*)d_in[9];
    const float* rph    = (const float*)d_in[10];
    const float* rpw    = (const float*)d_in[11];
    const float* ln2_w  = (const float*)d_in[12];
    const float* ln2_b  = (const float*)d_in[13];
    const float* fc1_w  = (const float*)d_in[14];
    const float* fc1_b  = (const float*)d_in[15];
    const float* fc2_w  = (const float*)d_in[16];
    const float* fc2_b  = (const float*)d_in[17];

    char* p = (char*)d_ws;
    float*           h       = (float*)p;           p += (size_t)M_ROWS*EMBED*4;
    __hip_bfloat16*  q_perm  = (__hip_bfloat16*)p;
    float*           p0      = (float*)p;           p += (size_t)48*NTOK*HD*2;
    __hip_bfloat16*  k_perm  = (__hip_bfloat16*)p;  p += (size_t)48*NTOK*HD*2;
    __hip_bfloat16*  vt_perm = (__hip_bfloat16*)p;  p += (size_t)48*NTOK*HD*2;
    __hip_bfloat16*  attn_o  = (__hip_bfloat16*)p;  p += (size_t)M_ROWS*EMBED*2;
    __hip_bfloat16*  x_ln    = (__hip_bfloat16*)p;  p += (size_t)M_ROWS*EMBED*2;
    __hip_bfloat16*  mlp     = (__hip_bfloat16*)p;  p += (size_t)M_ROWS*MLPD*2;
    __hip_bfloat16*  qkv_wt  = (__hip_bfloat16*)p;  p += (size_t)2304*768*2;
    __hip_bfloat16*  proj_wt = (__hip_bfloat16*)p;  p += (size_t)768*768*2;
    __hip_bfloat16*  fc1_wt  = (__hip_bfloat16*)p;  p += (size_t)MLPD*768*2;
    __hip_bfloat16*  fc2_wt  = (__hip_bfloat16*)p;  p += (size_t)768*MLPD*2;

    __hip_bfloat16*  A_im    = mlp;      // alias: not simultaneously live
    __hip_bfloat16*  conv_wt = qkv_wt;   // alias: overwritten by layer-0 prep

    // ---- patch embed as GEMM (64x128 tiles) ----
    im2col<<<M_ROWS, 256, 0, stream>>>(x, A_im);
    cvt_bf16<<<(768*768 + 255)/256, 256, 0, stream>>>(conv_w, conv_wt, 768*768);
    gemm64<<<dim3(768/128, M_ROWS/64, 1), 256, 0, stream>>>(
        A_im, conv_wt, conv_b, nullptr, pos, h, M_ROWS, 768, 768);

    layernorm_bf16<<<M_ROWS, 256, 0, stream>>>(h, ln1_w, ln1_b, x_ln);

    for (int L = 0; L < 4; ++L) {
        prep_weights<<<6912, 256, 0, stream>>>(
            qkv_w + (size_t)L*768*2304, proj_w + (size_t)L*768*768,
            fc1_w + (size_t)L*768*MLPD, fc2_w + (size_t)L*MLPD*768,
            qkv_wt, proj_wt, fc1_wt, fc2_wt);

        gemm128<<<dim3(2304/128, M_ROWS/128, 1), 256, 0, stream>>>(
            x_ln, qkv_wt, qkv_b + (size_t)L*3*EMBED,
            nullptr, nullptr, q_perm, k_perm, vt_perm,
            M_ROWS, 2304, 768, 1, 0, 2);

        attention_mfma<<<48*16, 256, 0, stream>>>(
            q_perm, k_perm, vt_perm,
            rph + (size_t)L*63*64, rpw + (size_t)L*63*64, attn_o);

        gemm64<<<dim3(768/128, M_ROWS/64, 1), 256, 0, stream>>>(
            attn_o, proj_wt, proj_b + (size_t)L*EMBED, h, nullptr,
            h, M_ROWS, 768, 768);

        layernorm_bf16<<<M_ROWS, 256, 0, stream>>>(h, ln2_w + L*EMBED, ln2_b + L*EMBED, x_ln);

        gemm128<<<dim3(MLPD/128, M_ROWS/128, 1), 256, 0, stream>>>(
            x_ln, fc1_wt, fc1_b + (size_t)L*MLPD,
            nullptr, mlp, nullptr, nullptr, nullptr,
            M_ROWS, MLPD, 768, 1, 1, 1);

        // fc2 split-K=2 -> fp32 partials p0,p1 (alias dead q/k/vt/attn_o region)
        gemm128<<<dim3(768/128, M_ROWS/128, 2), 256, 0, stream>>>(
            mlp, fc2_wt, nullptr,
            p0, nullptr, nullptr, nullptr, nullptr,
            M_ROWS, 768, MLPD, 2, 0, 3);

        float* p1 = p0 + (size_t)M_ROWS*768;
        if (L < 3) {
            resum_ln<<<M_ROWS, 256, 0, stream>>>(
                h, p0, p1, fc2_b + (size_t)L*EMBED,
                ln1_w + (size_t)(L+1)*EMBED, ln1_b + (size_t)(L+1)*EMBED, x_ln);
        } else {
            resum_out<<<M_ROWS*EMBED/256, 256, 0, stream>>>(
                h, p0, p1, fc2_b + (size_t)L*EMBED, (float*)d_out);
        }
    }
}

// Round 10
// 852.497 us; speedup vs baseline: 1.0801x; 1.0006x over previous
//
#include <hip/hip_runtime.h>
#include <hip/hip_bf16.h>
#include <math.h>
#include <stdint.h>

#define EMBED 768
#define NTOK  1024   // 32*32
#define BATCH 4
#define NHEAD 12
#define HD    64
#define MLPD  3072
#define M_ROWS 4096  // BATCH*NTOK

typedef __attribute__((ext_vector_type(8))) short short8;   // 8 x bf16 (4 VGPRs)
typedef __attribute__((ext_vector_type(4))) float floatx4;

__device__ __forceinline__ float b2f(__hip_bfloat16 v) { return __bfloat162float(v); }

// async global->LDS, 16B per lane (GEMM staging; layout lane-contiguous).
__device__ __forceinline__ void gld_lds16(const void* g, void* l) {
    __builtin_amdgcn_global_load_lds(
        (const __attribute__((address_space(1))) uint32_t*)g,
        (__attribute__((address_space(3))) uint32_t*)l, 16, 0, 0);
}

// XOR swizzle for attention tiles: chunk c (8 bf16) of row r at r*64 + ((c^(r&7))*8).
__device__ __forceinline__ int swz(int row, int c) { return row*64 + (((c) ^ (row & 7)) << 3); }

// Bijective XCD-chunked remap (m204 form).
__device__ __forceinline__ void xcd_remap(int gx, int gy, int& bx, int& by) {
    int id  = blockIdx.x + gx*blockIdx.y;
    int nwg = gx*gy;
    int q = nwg >> 3, r = nwg & 7;
    int xcd = id & 7, idx = id >> 3;
    int nid = (xcd < r ? xcd*(q+1) : r*(q+1) + (xcd-r)*q) + idx;
    bx = nid % gx;
    by = nid / gx;
}

// ---------------- im2col: x (4,3,512,512) fp32 -> A_im (4096,768) bf16 --------------
__global__ __launch_bounds__(256)
void im2col(const float* __restrict__ x, __hip_bfloat16* __restrict__ A)
{
    int p  = blockIdx.x;
    int b  = p >> 10;
    int n  = p & 1023;
    int gh = n >> 5, gw = n & 31;
    int tid = threadIdx.x;
    for (int i = tid; i < 768; i += 256) {
        int ci = i >> 8, r = i & 255, kh = r >> 4, kw = r & 15;
        A[(size_t)p*768 + i] = __float2bfloat16(
            x[(((size_t)b*3 + ci)*512 + (gh*16 + kh))*512 + gw*16 + kw]);
    }
}

// ---------------- elementwise fp32 -> bf16 cast -------------------------------------
__global__ __launch_bounds__(256)
void cvt_bf16(const float* __restrict__ in, __hip_bfloat16* __restrict__ out, int n)
{
    int i = blockIdx.x*256 + threadIdx.x;
    if (i < n) out[i] = __float2bfloat16(in[i]);
}

// ---------------- layernorm: fp32 in -> bf16 out ------------------------------------
__global__ __launch_bounds__(256)
void layernorm_bf16(const float* __restrict__ in,
                    const float* __restrict__ w,
                    const float* __restrict__ b,
                    __hip_bfloat16* __restrict__ out)
{
    int row = blockIdx.x;
    const float* xr = in + (size_t)row*768;
    int tid = threadIdx.x;
    float v0 = xr[tid], v1 = xr[tid+256], v2 = xr[tid+512];
    float s = v0+v1+v2, ss = v0*v0+v1*v1+v2*v2;
    __shared__ float rs[256], rss[256];
    rs[tid] = s; rss[tid] = ss; __syncthreads();
    for (int o = 128; o > 0; o >>= 1) {
        if (tid < o) { rs[tid] += rs[tid+o]; rss[tid] += rss[tid+o]; }
        __syncthreads();
    }
    float mean = rs[0] * (1.f/768.f);
    float var  = rss[0] * (1.f/768.f) - mean*mean;
    float inv  = rsqrtf(var + 1e-5f);
    out[(size_t)row*768 + tid]     = __float2bfloat16((v0-mean)*inv*w[tid]     + b[tid]);
    out[(size_t)row*768 + tid+256] = __float2bfloat16((v1-mean)*inv*w[tid+256] + b[tid+256]);
    out[(size_t)row*768 + tid+512] = __float2bfloat16((v2-mean)*inv*w[tid+512] + b[tid+512]);
}

// ---------------- fused: h += p0+p1+bias ; x_ln = LN(h) (next layer ln1) ------------
__global__ __launch_bounds__(256)
void resum_ln(float* __restrict__ h,
              const float* __restrict__ p0, const float* __restrict__ p1,
              const float* __restrict__ bias,
              const float* __restrict__ w, const float* __restrict__ b,
              __hip_bfloat16* __restrict__ out)
{
    int row = blockIdx.x;
    int tid = threadIdx.x;
    size_t base = (size_t)row*768;
    float v[3];
    float s = 0.f, ss = 0.f;
    #pragma unroll
    for (int e = 0; e < 3; ++e) {
        int i = tid + e*256;
        float val = h[base+i] + p0[base+i] + p1[base+i] + bias[i];
        h[base+i] = val;
        v[e] = val; s += val; ss += val*val;
    }
    __shared__ float rs[256], rss[256];
    rs[tid] = s; rss[tid] = ss; __syncthreads();
    for (int o = 128; o > 0; o >>= 1) {
        if (tid < o) { rs[tid] += rs[tid+o]; rss[tid] += rss[tid+o]; }
        __syncthreads();
    }
    float mean = rs[0] * (1.f/768.f);
    float var  = rss[0] * (1.f/768.f) - mean*mean;
    float inv  = rsqrtf(var + 1e-5f);
    #pragma unroll
    for (int e = 0; e < 3; ++e) {
        int i = tid + e*256;
        out[base+i] = __float2bfloat16((v[e]-mean)*inv*w[i] + b[i]);
    }
}

// ---------------- final: out = h + p0 + p1 + bias (fp32) ----------------------------
__global__ __launch_bounds__(256)
void resum_out(const float* __restrict__ h,
               const float* __restrict__ p0, const float* __restrict__ p1,
               const float* __restrict__ bias,
               float* __restrict__ out)
{
    int i = blockIdx.x*256 + threadIdx.x;
    out[i] = h[i] + p0[i] + p1[i] + bias[i % 768];
}

// ---------------- merged weight prep: 4 transposes in one launch --------------------
__global__ __launch_bounds__(256)
void prep_weights(const float* __restrict__ qkv_w,  const float* __restrict__ proj_w,
                  const float* __restrict__ fc1_w,  const float* __restrict__ fc2_w,
                  __hip_bfloat16* __restrict__ qkv_wt, __hip_bfloat16* __restrict__ proj_wt,
                  __hip_bfloat16* __restrict__ fc1_wt, __hip_bfloat16* __restrict__ fc2_wt)
{
    int id = blockIdx.x;
    const float* src; __hip_bfloat16* dst; int K, N, bx, by;
    if (id < 1728)      {            src = qkv_w;  dst = qkv_wt;  K = 768;  N = 2304; bx = id % 72; by = id / 72; }
    else if (id < 2304) { id -= 1728; src = proj_w; dst = proj_wt; K = 768;  N = 768;  bx = id % 24; by = id / 24; }
    else if (id < 4608) { id -= 2304; src = fc1_w;  dst = fc1_wt;  K = 768;  N = 3072; bx = id % 96; by = id / 96; }
    else                { id -= 4608; src = fc2_w;  dst = fc2_wt;  K = 3072; N = 768;  bx = id % 24; by = id / 24; }

    __shared__ float t[32][33];
    int n0 = bx*32, k0 = by*32;
    int tx = threadIdx.x & 31, ty = threadIdx.x >> 5;   // (32, 8)
    #pragma unroll
    for (int r = 0; r < 4; ++r) {
        int row = ty + r*8;
        t[row][tx] = src[(size_t)(k0+row)*N + n0 + tx];
    }
    __syncthreads();
    #pragma unroll
    for (int r = 0; r < 4; ++r) {
        int row = ty + r*8;
        dst[(size_t)(n0+row)*K + k0 + tx] = __float2bfloat16(t[tx][row]);
    }
}

// ---------------- MFMA GEMM, 64x128 tile, 3-buffer single-barrier pipeline ----------
// grid (N/128, M/64). 4 waves 2x2: wave = 32 rows x 64 cols (2x4 mfma accs).
// fp32 out (+res, +posadd). One barrier per K-step; stage(t+2) into buf[(t+2)%3]
// (last read at step t-1, provably drained before barrier(t)).
__global__ __launch_bounds__(256, 3)
void gemm64(const __hip_bfloat16* __restrict__ A,
            const __hip_bfloat16* __restrict__ Bt,
            const float* __restrict__ bias,
            const float* __restrict__ res,
            const float* __restrict__ posadd,
            float* __restrict__ Cf,
            int M, int N, int K)
{
    // three 12 KB staging buffers: As 64x32 (4 KB) + Bs 128x32 (8 KB) each
    __shared__ __align__(16) char smem[36864];

    const int tid  = threadIdx.x;
    const int lane = tid & 63;
    const int wid  = tid >> 6;
    const int wr   = wid >> 1;          // 0..1 : 32-row half
    const int wc   = wid & 1;           // 0..1 : 64-col half
    const int lr   = lane & 15;
    const int quad = lane >> 4;

    int bx, by;
    xcd_remap(gridDim.x, gridDim.y, bx, by);
    const int bm = by * 64;
    const int bn = bx * 128;

    const int srow  = tid >> 2;         // 0..63
    // bank-deconflict: physical chunk c holds logical chunk c ^ ((row>>1)&3)
    const int skoff = ((tid & 3) ^ ((tid >> 3) & 3)) * 8;
    const int csw   = (quad ^ ((lr >> 1) & 3)) * 8;

    floatx4 acc[2][4];
    #pragma unroll
    for (int i = 0; i < 2; ++i)
        #pragma unroll
        for (int j = 0; j < 4; ++j)
            acc[i][j] = (floatx4){0.f,0.f,0.f,0.f};

    auto stage = [&](int bq, int k0) {
        char* base = smem + bq*12288 + (wid * 1024);
        gld_lds16(A + (size_t)(bm + srow)*K + k0 + skoff, base);
        #pragma unroll
        for (int c = 0; c < 2; ++c)
            gld_lds16(Bt + (size_t)(bn + c*64 + srow)*K + k0 + skoff,
                      base + 4096 + c*4096);
    };

    const int nt = K >> 5;              // 24 for all uses
    stage(0, 0);
    stage(1, 32);
    int rcur = 0;                       // buffer holding step t
    for (int t = 0; t < nt; ++t) {
        // own stage(t) = 3 oldest loads; stage(t+1) (3) may stay in flight
        if (t + 1 < nt) asm volatile("s_waitcnt vmcnt(3)" ::: "memory");
        else            asm volatile("s_waitcnt vmcnt(0)" ::: "memory");
        __builtin_amdgcn_s_barrier();

        const __hip_bfloat16* As = (const __hip_bfloat16*)(smem + rcur*12288);
        const __hip_bfloat16* Bs = As + 2048;   // +4096 bytes

        short8 a[2], b[4];
        #pragma unroll
        for (int i = 0; i < 2; ++i)
            a[i] = *(const short8*)((const void*)(As + (wr*32 + i*16 + lr)*32 + csw));
        #pragma unroll
        for (int j = 0; j < 4; ++j)
            b[j] = *(const short8*)((const void*)(Bs + (wc*64 + j*16 + lr)*32 + csw));

        if (t + 2 < nt) {
            int sb = rcur + 2; if (sb >= 3) sb -= 3;
            stage(sb, (t+2)*32);
        }

        asm volatile("s_waitcnt lgkmcnt(0)" ::: "memory");
        __builtin_amdgcn_sched_barrier(0);

        #pragma unroll
        for (int i = 0; i < 2; ++i)
            #pragma unroll
            for (int j = 0; j < 4; ++j)
                acc[i][j] = __builtin_amdgcn_mfma_f32_16x16x32_bf16(a[i], b[j], acc[i][j], 0, 0, 0);
        rcur = (rcur == 2) ? 0 : rcur + 1;
    }

    // fp32 out (+res, +posadd): direct 64B-chunk stores
    #pragma unroll
    for (int j = 0; j < 4; ++j) {
        int col = bn + wc*64 + j*16 + lr;
        float bs = bias[col];
        #pragma unroll
        for (int i = 0; i < 2; ++i) {
            #pragma unroll
            for (int r = 0; r < 4; ++r) {
                int row = bm + wr*32 + i*16 + quad*4 + r;
                float val = acc[i][j][r] + bs;
                if (res)    val += res[(size_t)row*N + col];
                if (posadd) val += posadd[(size_t)(row & 1023)*N + col];
                Cf[(size_t)row*N + col] = val;
            }
        }
    }
}

// ---------------- MFMA GEMM, 128x128 tile, 3-buffer single-barrier pipeline ---------
// grid (N/128, M/128, S). 4 waves 2x2: wave = 64 rows x 64 cols (4x4 mfma accs).
// emode 1: bf16 Cb (+gelu); emode 2: qkv permute; emode 3: fp32 split-K partial.
__global__ __launch_bounds__(256, 3)
void gemm128(const __hip_bfloat16* __restrict__ A,
             const __hip_bfloat16* __restrict__ Bt,
             const float* __restrict__ bias,
             float* __restrict__ Cf,
             __hip_bfloat16* __restrict__ Cb,
             __hip_bfloat16* __restrict__ qp,
             __hip_bfloat16* __restrict__ kp,
             __hip_bfloat16* __restrict__ vp,
             int M, int N, int K, int S, int dogelu, int emode)
{
    // three 16 KB staging buffers (As 8 KB + Bs 8 KB each); epilogue scratch
    // (4 x 4864 B) aliases the low buffers after the post-loop barrier.
    __shared__ __align__(16) char smem[49152];

    const int tid  = threadIdx.x;
    const int lane = tid & 63;
    const int wid  = tid >> 6;
    const int wr   = wid >> 1;          // 0..1 : 64-row half
    const int wc   = wid & 1;           // 0..1 : 64-col half
    const int lr   = lane & 15;
    const int quad = lane >> 4;

    int bx, by;
    xcd_remap(gridDim.x, gridDim.y, bx, by);
    const int bm = by * 128;
    const int bn = bx * 128;
    const int z  = blockIdx.z;
    const int Kseg = K / S;
    const int kbeg = z * Kseg;

    const int srow  = tid >> 2;         // 0..63
    const int skoff = ((tid & 3) ^ ((tid >> 3) & 3)) * 8;
    const int csw   = (quad ^ ((lr >> 1) & 3)) * 8;

    floatx4 acc[4][4];
    #pragma unroll
    for (int i = 0; i < 4; ++i)
        #pragma unroll
        for (int j = 0; j < 4; ++j)
            acc[i][j] = (floatx4){0.f,0.f,0.f,0.f};

    auto stage = [&](int bq, int k0) {
        char* base = smem + bq*16384 + (wid * 1024);
        #pragma unroll
        for (int c = 0; c < 2; ++c)
            gld_lds16(A + (size_t)(bm + c*64 + srow)*K + k0 + skoff,
                      base + c*4096);
        #pragma unroll
        for (int c = 0; c < 2; ++c)
            gld_lds16(Bt + (size_t)(bn + c*64 + srow)*K + k0 + skoff,
                      base + 8192 + c*4096);
    };

    const int nt = Kseg >> 5;           // 24 or 48
    stage(0, kbeg);
    stage(1, kbeg + 32);
    int rcur = 0;                       // buffer holding step t
    for (int t = 0; t < nt; ++t) {
        // own stage(t) = 4 oldest loads; stage(t+1) (4) may stay in flight
        if (t + 1 < nt) asm volatile("s_waitcnt vmcnt(4)" ::: "memory");
        else            asm volatile("s_waitcnt vmcnt(0)" ::: "memory");
        __builtin_amdgcn_s_barrier();

        const __hip_bfloat16* As = (const __hip_bfloat16*)(smem + rcur*16384);
        const __hip_bfloat16* Bs = As + 4096;   // +8192 bytes

        short8 a[4], b[4];
        #pragma unroll
        for (int i = 0; i < 4; ++i)
            a[i] = *(const short8*)((const void*)(As + (wr*64 + i*16 + lr)*32 + csw));
        #pragma unroll
        for (int j = 0; j < 4; ++j)
            b[j] = *(const short8*)((const void*)(Bs + (wc*64 + j*16 + lr)*32 + csw));

        if (t + 2 < nt) {
            int sb = rcur + 2; if (sb >= 3) sb -= 3;
            stage(sb, kbeg + (t+2)*32);
        }

        asm volatile("s_waitcnt lgkmcnt(0)" ::: "memory");
        __builtin_amdgcn_sched_barrier(0);

        #pragma unroll
        for (int i = 0; i < 4; ++i)
            #pragma unroll
            for (int j = 0; j < 4; ++j)
                acc[i][j] = __builtin_amdgcn_mfma_f32_16x16x32_bf16(a[i], b[j], acc[i][j], 0, 0, 0);
        rcur = (rcur == 2) ? 0 : rcur + 1;
    }
    // all waves' reads drained (lgkmcnt(0) before their last mfma); barrier before
    // reusing staging LDS as epilogue scratch.
    __builtin_amdgcn_s_barrier();

    if (emode == 3) {
        // fp32 partials, no bias
        #pragma unroll
        for (int j = 0; j < 4; ++j) {
            int col = bn + wc*64 + j*16 + lr;
            #pragma unroll
            for (int i = 0; i < 4; ++i) {
                #pragma unroll
                for (int r = 0; r < 4; ++r) {
                    int row = bm + wr*64 + i*16 + quad*4 + r;
                    Cf[(size_t)z*M*N + (size_t)row*N + col] = acc[i][j][r];
                }
            }
        }
        return;
    }

    __hip_bfloat16* epi = (__hip_bfloat16*)(smem + wid*4864);

    if (emode == 1) {
        // bf16 out (+gelu), 2 passes of 32 rows through per-wave LDS scratch
        #pragma unroll
        for (int p = 0; p < 2; ++p) {
            #pragma unroll
            for (int j = 0; j < 4; ++j) {
                float bs = bias[bn + wc*64 + j*16 + lr];
                #pragma unroll
                for (int ii = 0; ii < 2; ++ii) {
                    int i = p*2 + ii;
                    #pragma unroll
                    for (int r = 0; r < 4; ++r) {
                        float val = acc[i][j][r] + bs;
                        if (dogelu) val = 0.5f*val*(1.f + erff(val*0.70710678118f));
                        epi[(ii*16 + quad*4 + r)*72 + j*16 + lr] = __float2bfloat16(val);
                    }
                }
            }
            #pragma unroll
            for (int p2 = 0; p2 < 4; ++p2) {
                int row = p2*8 + (lane >> 3), chunk = lane & 7;
                short8 v = *(const short8*)((const void*)(epi + row*72 + chunk*8));
                *(short8*)((void*)(Cb + (size_t)(bm + wr*64 + p*32 + row)*N
                                      + bn + wc*64 + chunk*8)) = v;
            }
        }
        return;
    }

    // emode 2: qkv permute
    const int head64 = (bn + wc*64) >> 6;     // wave's 64 cols = one head slot
    const int which  = head64 / 12;           // 0=q 1=k 2=v
    const int head   = head64 % 12;
    const int b_     = (bm + wr*64) >> 10;
    const int bh     = b_*NHEAD + head;
    const int n0     = (bm + wr*64) & 1023;

    if (which < 2) {
        __hip_bfloat16* dst = (which == 0 ? qp : kp) + ((size_t)bh*NTOK + n0)*HD;
        #pragma unroll
        for (int p = 0; p < 2; ++p) {
            #pragma unroll
            for (int j = 0; j < 4; ++j) {
                float bs = bias[bn + wc*64 + j*16 + lr];
                #pragma unroll
                for (int ii = 0; ii < 2; ++ii) {
                    int i = p*2 + ii;
                    #pragma unroll
                    for (int r = 0; r < 4; ++r)
                        epi[(ii*16 + quad*4 + r)*72 + j*16 + lr] =
                            __float2bfloat16(acc[i][j][r] + bs);
                }
            }
            #pragma unroll
            for (int p2 = 0; p2 < 4; ++p2) {
                int row = p2*8 + (lane >> 3), chunk = lane & 7;
                short8 v = *(const short8*)((const void*)(epi + row*72 + chunk*8));
                *(short8*)((void*)(dst + (size_t)(p*32 + row)*HD + chunk*8)) = v;
            }
        }
    } else {
        // v transposed: [d=64][tok32] per pass, stride 36
        __hip_bfloat16* dstv = vp + (size_t)bh*HD*NTOK + n0;
        #pragma unroll
        for (int p = 0; p < 2; ++p) {
            #pragma unroll
            for (int j = 0; j < 4; ++j) {
                float bs = bias[bn + wc*64 + j*16 + lr];
                #pragma unroll
                for (int ii = 0; ii < 2; ++ii) {
                    int i = p*2 + ii;
                    #pragma unroll
                    for (int r = 0; r < 4; ++r)
                        epi[(j*16 + lr)*36 + ii*16 + quad*4 + r] =
                            __float2bfloat16(acc[i][j][r] + bs);
                }
            }
            #pragma unroll
            for (int p2 = 0; p2 < 4; ++p2) {
                int d = p2*16 + (lane >> 2), chunk = lane & 3;
                short8 v = *(const short8*)((const void*)(epi + d*36 + chunk*8));
                *(short8*)((void*)(dstv + (size_t)d*NTOK + p*32 + chunk*8)) = v;
            }
        }
    }
}

// ---------------- MFMA flash attention, swizzled LDS, shift-free softmax ------------
__global__ __launch_bounds__(256)
void attention_mfma(const __hip_bfloat16* __restrict__ qp,   // [48][1024][64]
                    const __hip_bfloat16* __restrict__ kp,   // [48][1024][64]
                    const __hip_bfloat16* __restrict__ vp,   // [48][64][1024] (V^T)
                    const float* __restrict__ rph,           // (63,64)
                    const float* __restrict__ rpw,           // (63,64)
                    __hip_bfloat16* __restrict__ out)        // (4,1024,768) bf16
{
    const int blk  = blockIdx.x;
    const int bh   = blk >> 4;
    const int qt   = blk & 15;
    const int b    = bh / NHEAD;
    const int head = bh % NHEAD;
    const int tid  = threadIdx.x;
    const int lane = tid & 63;
    const int w    = tid >> 6;
    const int lr   = lane & 15;
    const int quad = lane >> 4;

    __shared__ __align__(16) __hip_bfloat16 Qs[64*64];
    __shared__ __align__(16) __hip_bfloat16 Ks[64*64];      // prologue alias: rph table
    __shared__ __align__(16) __hip_bfloat16 Vs[64*64];      // prologue alias: rpw table
    __shared__ __align__(16) __hip_bfloat16 Ps[4*16*64];
    __shared__ float relhS[64*32];
    __shared__ float relwS[64*32];

    const __hip_bfloat16* qb = qp + ((size_t)bh*NTOK + qt*64)*HD;
    const __hip_bfloat16* kb = kp + (size_t)bh*NTOK*HD;
    const __hip_bfloat16* vb = vp + (size_t)bh*HD*NTOK;

    const int sr = tid >> 2;
    const int sc = (tid & 3) * 2;

    short8 kreg0, kreg1, vreg0, vreg1;
    {
        const __hip_bfloat16* kk = kb + (size_t)sr*HD + sc*8;
        kreg0 = *(const short8*)((const void*)kk);
        kreg1 = *(const short8*)((const void*)(kk + 8));
        const __hip_bfloat16* vv = vb + (size_t)sr*NTOK + sc*8;
        vreg0 = *(const short8*)((const void*)vv);
        vreg1 = *(const short8*)((const void*)(vv + 8));
    }

    {
        const __hip_bfloat16* qq = qb + (size_t)sr*HD + sc*8;
        short8 q0 = *(const short8*)((const void*)qq);
        short8 q1 = *(const short8*)((const void*)(qq + 8));
        *(short8*)((void*)(Qs + swz(sr, sc)))   = q0;
        *(short8*)((void*)(Qs + swz(sr, sc+1))) = q1;
    }

    for (int i = tid; i < 504; i += 256) {
        int r = i >> 3, c = i & 7;
        const float* ph = rph + (size_t)r*HD + c*8;
        const float* pw = rpw + (size_t)r*HD + c*8;
        union { short8 v; __hip_bfloat16 e[8]; } uh, uw;
        #pragma unroll
        for (int e = 0; e < 8; ++e) { uh.e[e] = __float2bfloat16(ph[e]); uw.e[e] = __float2bfloat16(pw[e]); }
        *(short8*)((void*)(Ks + swz(r, c))) = uh.v;
        *(short8*)((void*)(Vs + swz(r, c))) = uw.v;
    }
    if (tid < 16) {
        short8 z = (short8){0,0,0,0,0,0,0,0};
        int c = tid & 7;
        if (tid < 8) *(short8*)((void*)(Ks + swz(63, c))) = z;
        else         *(short8*)((void*)(Vs + swz(63, c))) = z;
    }
    __syncthreads();

    short8 qa0 = *(const short8*)((const void*)(Qs + swz(w*16 + lr, quad)));
    short8 qa1 = *(const short8*)((const void*)(Qs + swz(w*16 + lr, 4 + quad)));

    const int qrow = w*16 + quad*4;
    const int qh_  = qt*2 + (w >> 1);
    const int qw_  = (w & 1)*16 + quad*4;

    #pragma unroll
    for (int j = 0; j < 4; ++j) {
        int t = j*16 + lr;
        short8 th0 = *(const short8*)((const void*)(Ks + swz(j*16 + lr, quad)));
        short8 th1 = *(const short8*)((const void*)(Ks + swz(j*16 + lr, 4 + quad)));
        floatx4 ha = (floatx4){0.f,0.f,0.f,0.f};
        ha = __builtin_amdgcn_mfma_f32_16x16x32_bf16(qa0, th0, ha, 0, 0, 0);
        ha = __builtin_amdgcn_mfma_f32_16x16x32_bf16(qa1, th1, ha, 0, 0, 0);
        short8 tw0 = *(const short8*)((const void*)(Vs + swz(j*16 + lr, quad)));
        short8 tw1 = *(const short8*)((const void*)(Vs + swz(j*16 + lr, 4 + quad)));
        floatx4 wa = (floatx4){0.f,0.f,0.f,0.f};
        wa = __builtin_amdgcn_mfma_f32_16x16x32_bf16(qa0, tw0, wa, 0, 0, 0);
        wa = __builtin_amdgcn_mfma_f32_16x16x32_bf16(qa1, tw1, wa, 0, 0, 0);
        int kh = qh_ + 31 - t;
        #pragma unroll
        for (int rr = 0; rr < 4; ++rr) {
            if (kh >= 0 && kh < 32) relhS[(qrow + rr)*32 + kh] = ha[rr];
            int kw = qw_ + rr + 31 - t;
            if (kw >= 0 && kw < 32) relwS[(qrow + rr)*32 + kw] = wa[rr];
        }
    }

    float rw[4][2];
    #pragma unroll
    for (int rr = 0; rr < 4; ++rr)
        #pragma unroll
        for (int jp = 0; jp < 2; ++jp)
            rw[rr][jp] = relwS[(qrow + rr)*32 + jp*16 + lr];

    floatx4 o[4];
    #pragma unroll
    for (int ds = 0; ds < 4; ++ds) o[ds] = (floatx4){0.f,0.f,0.f,0.f};
    float lsum[4] = {0.f, 0.f, 0.f, 0.f};

    const float scale = 0.125f;

    for (int kt = 0; kt < 16; ++kt) {
        __syncthreads();
        *(short8*)((void*)(Ks + swz(sr, sc)))   = kreg0;
        *(short8*)((void*)(Ks + swz(sr, sc+1))) = kreg1;
        *(short8*)((void*)(Vs + swz(sr, sc)))   = vreg0;
        *(short8*)((void*)(Vs + swz(sr, sc+1))) = vreg1;
        __syncthreads();

        if (kt < 15) {
            const __hip_bfloat16* kk = kb + (size_t)(kt+1)*64*HD + (size_t)sr*HD + sc*8;
            kreg0 = *(const short8*)((const void*)kk);
            kreg1 = *(const short8*)((const void*)(kk + 8));
            const __hip_bfloat16* vv = vb + (size_t)sr*NTOK + (kt+1)*64 + sc*8;
            vreg0 = *(const short8*)((const void*)vv);
            vreg1 = *(const short8*)((const void*)(vv + 8));
        }

        float2 rh2[4];
        #pragma unroll
        for (int rr = 0; rr < 4; ++rr)
            rh2[rr] = *(const float2*)((const void*)(relhS + (qrow + rr)*32 + kt*2));

        floatx4 sv[4];
        #pragma unroll
        for (int j = 0; j < 4; ++j) {
            short8 kb0 = *(const short8*)((const void*)(Ks + swz(j*16 + lr, quad)));
            short8 kb1 = *(const short8*)((const void*)(Ks + swz(j*16 + lr, 4 + quad)));
            floatx4 z = (floatx4){0.f,0.f,0.f,0.f};
            z = __builtin_amdgcn_mfma_f32_16x16x32_bf16(qa0, kb0, z, 0, 0, 0);
            z = __builtin_amdgcn_mfma_f32_16x16x32_bf16(qa1, kb1, z, 0, 0, 0);
            sv[j] = z;
        }

        #pragma unroll
        for (int j = 0; j < 4; ++j) {
            int colc = j*2 + (lr >> 3);
            #pragma unroll
            for (int rr = 0; rr < 4; ++rr) {
                float s = sv[j][rr]*scale + ((j < 2) ? rh2[rr].x : rh2[rr].y) + rw[rr][j & 1];
                s = fminf(fmaxf(s, -60.f), 60.f);
                float pp = __expf(s);
                lsum[rr] += pp;
                int prow = quad*4 + rr;
                Ps[w*1024 + prow*64 + ((colc ^ (prow & 7)) << 3) + (lr & 7)] = __float2bfloat16(pp);
            }
        }

        short8 pa0 = *(const short8*)((const void*)(Ps + w*1024 + swz(lr, quad)));
        short8 pa1 = *(const short8*)((const void*)(Ps + w*1024 + swz(lr, 4 + quad)));
        #pragma unroll
        for (int ds = 0; ds < 4; ++ds) {
            short8 v0 = *(const short8*)((const void*)(Vs + swz(ds*16 + lr, quad)));
            short8 v1 = *(const short8*)((const void*)(Vs + swz(ds*16 + lr, 4 + quad)));
            o[ds] = __builtin_amdgcn_mfma_f32_16x16x32_bf16(pa0, v0, o[ds], 0, 0, 0);
            o[ds] = __builtin_amdgcn_mfma_f32_16x16x32_bf16(pa1, v1, o[ds], 0, 0, 0);
        }
    }

    #pragma unroll
    for (int off = 1; off < 16; off <<= 1)
        #pragma unroll
        for (int rr = 0; rr < 4; ++rr)
            lsum[rr] += __shfl_xor(lsum[rr], off, 16);

    #pragma unroll
    for (int rr = 0; rr < 4; ++rr) {
        float inv = 1.f / lsum[rr];
        int n = qt*64 + w*16 + quad*4 + rr;
        size_t base = ((size_t)b*NTOK + n)*EMBED + head*HD;
        #pragma unroll
        for (int ds = 0; ds < 4; ++ds)
            out[base + ds*16 + lr] = __float2bfloat16(o[ds][rr] * inv);
    }
}

extern "C" void kernel_launch(void* const* d_in, const int* in_sizes, int n_in,
                              void* d_out, int out_size, void* d_ws, size_t ws_size,
                              hipStream_t stream)
{
    const float* x      = (const float*)d_in[0];
    const float* conv_w = (const float*)d_in[1];
    const float* conv_b = (const float*)d_in[2];
    const float* pos    = (const float*)d_in[3];
    const float* ln1_w  = (const float*)d_in[4];
    const float* ln1_b  = (const float*)d_in[5];
    const float* qkv_w  = (const float*)d_in[6];
    const float* qkv_b  = (const float*)d_in[7];
    const float* proj_w = (const float*)d_in[8];
    const float* proj_b = (const float*)d_in[9];
    const float* rph    = (const float*)d_in[10];
    const float* rpw    = (const float*)d_in[11];
    const float* ln2_w  = (const float*)d_in[12];
    const float* ln2_b  = (const float*)d_in[13];
    const float* fc1_w  = (const float*)d_in[14];
    const float* fc1_b  = (const float*)d_in[15];
    const float* fc2_w  = (const float*)d_in[16];
    const float* fc2_b  = (const float*)d_in[17];

    char* p = (char*)d_ws;
    float*           h       = (float*)p;           p += (size_t)M_ROWS*EMBED*4;
    __hip_bfloat16*  q_perm  = (__hip_bfloat16*)p;
    float*           p0      = (float*)p;           p += (size_t)48*NTOK*HD*2;
    __hip_bfloat16*  k_perm  = (__hip_bfloat16*)p;  p += (size_t)48*NTOK*HD*2;
    __hip_bfloat16*  vt_perm = (__hip_bfloat16*)p;  p += (size_t)48*NTOK*HD*2;
    __hip_bfloat16*  attn_o  = (__hip_bfloat16*)p;  p += (size_t)M_ROWS*EMBED*2;
    __hip_bfloat16*  x_ln    = (__hip_bfloat16*)p;  p += (size_t)M_ROWS*EMBED*2;
    __hip_bfloat16*  mlp     = (__hip_bfloat16*)p;  p += (size_t)M_ROWS*MLPD*2;
    __hip_bfloat16*  qkv_wt  = (__hip_bfloat16*)p;  p += (size_t)2304*768*2;
    __hip_bfloat16*  proj_wt = (__hip_bfloat16*)p;  p += (size_t)768*768*2;
    __hip_bfloat16*  fc1_wt  = (__hip_bfloat16*)p;  p += (size_t)MLPD*768*2;
    __hip_bfloat16*  fc2_wt  = (__hip_bfloat16*)p;  p += (size_t)768*MLPD*2;

    __hip_bfloat16*  A_im    = mlp;      // alias: not simultaneously live
    __hip_bfloat16*  conv_wt = qkv_wt;   // alias: overwritten by layer-0 prep

    // ---- patch embed as GEMM (64x128 tiles) ----
    im2col<<<M_ROWS, 256, 0, stream>>>(x, A_im);
    cvt_bf16<<<(768*768 + 255)/256, 256, 0, stream>>>(conv_w, conv_wt, 768*768);
    gemm64<<<dim3(768/128, M_ROWS/64, 1), 256, 0, stream>>>(
        A_im, conv_wt, conv_b, nullptr, pos, h, M_ROWS, 768, 768);

    layernorm_bf16<<<M_ROWS, 256, 0, stream>>>(h, ln1_w, ln1_b, x_ln);

    for (int L = 0; L < 4; ++L) {
        prep_weights<<<6912, 256, 0, stream>>>(
            qkv_w + (size_t)L*768*2304, proj_w + (size_t)L*768*768,
            fc1_w + (size_t)L*768*MLPD, fc2_w + (size_t)L*MLPD*768,
            qkv_wt, proj_wt, fc1_wt, fc2_wt);

        gemm128<<<dim3(2304/128, M_ROWS/128, 1), 256, 0, stream>>>(
            x_ln, qkv_wt, qkv_b + (size_t)L*3*EMBED,
            nullptr, nullptr, q_perm, k_perm, vt_perm,
            M_ROWS, 2304, 768, 1, 0, 2);

        attention_mfma<<<48*16, 256, 0, stream>>>(
            q_perm, k_perm, vt_perm,
            rph + (size_t)L*63*64, rpw + (size_t)L*63*64, attn_o);

        gemm64<<<dim3(768/128, M_ROWS/64, 1), 256, 0, stream>>>(
            attn_o, proj_wt, proj_b + (size_t)L*EMBED, h, nullptr,
            h, M_ROWS, 768, 768);

        layernorm_bf16<<<M_ROWS, 256, 0, stream>>>(h, ln2_w + L*EMBED, ln2_b + L*EMBED, x_ln);

        gemm128<<<dim3(MLPD/128, M_ROWS/128, 1), 256, 0, stream>>>(
            x_ln, fc1_wt, fc1_b + (size_t)L*MLPD,
            nullptr, mlp, nullptr, nullptr, nullptr,
            M_ROWS, MLPD, 768, 1, 1, 1);

        // fc2 split-K=2 -> fp32 partials p0,p1 (alias dead q/k/vt/attn_o region)
        gemm128<<<dim3(768/128, M_ROWS/128, 2), 256, 0, stream>>>(
            mlp, fc2_wt, nullptr,
            p0, nullptr, nullptr, nullptr, nullptr,
            M_ROWS, 768, MLPD, 2, 0, 3);

        float* p1 = p0 + (size_t)M_ROWS*768;
        if (L < 3) {
            resum_ln<<<M_ROWS, 256, 0, stream>>>(
                h, p0, p1, fc2_b + (size_t)L*EMBED,
                ln1_w + (size_t)(L+1)*EMBED, ln1_b + (size_t)(L+1)*EMBED, x_ln);
        } else {
            resum_out<<<M_ROWS*EMBED/256, 256, 0, stream>>>(
                h, p0, p1, fc2_b + (size_t)L*EMBED, (float*)d_out);
        }
    }
}